// Round 5
// baseline (2442.504 us; speedup 1.0000x reference)
//
#include <hip/hip_runtime.h>
#include <stdint.h>

#define NU 200000
#define NM 100000
#define DIM 64
#define SCAN_CHUNK 2048
#define MBK 8            // mega-buckets per direction
#define MB_M 12500       // movie node span per bucket (NM/8)
#define MB_U 25000       // user  node span per bucket (NU/8)

// ---------------------------------------------------------------------------
// Detect whether edge index arrays are int64 or int32.
__global__ void detect_idx_kernel(const unsigned int* __restrict__ words,
                                  int* __restrict__ flag) {
    __shared__ int nz;
    if (threadIdx.x == 0) nz = 0;
    __syncthreads();
    for (int i = threadIdx.x; i < 2048; i += blockDim.x)
        if (words[2 * i + 1] != 0u) nz = 1;
    __syncthreads();
    if (threadIdx.x == 0) *flag = (nz == 0) ? 1 : 0;   // 1 => int64
}

__device__ __forceinline__ int load_idx(const void* __restrict__ p, int e, int is64) {
    if (is64) return (int)((const long long*)p)[e];
    return ((const int*)p)[e];
}

// ---------------------------------------------------------------------------
// Degree histogram (per node, both directions) + 8-bucket mega histogram.
__global__ void count_kernel(const void* __restrict__ es, const void* __restrict__ ed,
                             const int* __restrict__ flag,
                             int* __restrict__ deg_u, int* __restrict__ deg_m,
                             int* __restrict__ cnt_mb, int* __restrict__ cnt_ub, int nE) {
    __shared__ int h[2 * MBK];
    if (threadIdx.x < 2 * MBK) h[threadIdx.x] = 0;
    __syncthreads();
    const int is64 = *flag;
    const int stride = gridDim.x * blockDim.x;
    for (int e = blockIdx.x * blockDim.x + threadIdx.x; e < nE; e += stride) {
        int s = load_idx(es, e, is64);
        int d = load_idx(ed, e, is64);
        atomicAdd(&deg_u[s], 1);
        atomicAdd(&deg_m[d], 1);
        atomicAdd(&h[(unsigned)d / MB_M], 1);
        atomicAdd(&h[MBK + (unsigned)s / MB_U], 1);
    }
    __syncthreads();
    if (threadIdx.x < MBK) {
        if (h[threadIdx.x]) atomicAdd(&cnt_mb[threadIdx.x], h[threadIdx.x]);
    } else if (threadIdx.x < 2 * MBK) {
        if (h[threadIdx.x]) atomicAdd(&cnt_ub[threadIdx.x - MBK], h[threadIdx.x]);
    }
}

// ---------------------------------------------------------------------------
// Exclusive scan over n ints, 3 phases (chunk = 2048 = 256 thr x 8).
__global__ void scan_block_sums(const int* __restrict__ a, int* __restrict__ bsum, int n) {
    int base = blockIdx.x * SCAN_CHUNK + threadIdx.x * 8;
    int tot = 0;
#pragma unroll
    for (int k = 0; k < 8; ++k) { int i = base + k; if (i < n) tot += a[i]; }
    __shared__ int sc[256];
    sc[threadIdx.x] = tot;
    __syncthreads();
    for (int off = 128; off > 0; off >>= 1) {
        if (threadIdx.x < off) sc[threadIdx.x] += sc[threadIdx.x + off];
        __syncthreads();
    }
    if (threadIdx.x == 0) bsum[blockIdx.x] = sc[0];
}

__global__ void scan_bsum(int* __restrict__ bsum, int nb) {
    if (blockIdx.x == 0 && threadIdx.x == 0) {
        int acc = 0;
        for (int i = 0; i < nb; ++i) { int v = bsum[i]; bsum[i] = acc; acc += v; }
    }
}

__global__ void scan_apply(int* __restrict__ a, const int* __restrict__ bsum, int n, int nE) {
    const int t = threadIdx.x;
    int base = blockIdx.x * SCAN_CHUNK + t * 8;
    int v[8];
    int tot = 0;
#pragma unroll
    for (int k = 0; k < 8; ++k) { int i = base + k; v[k] = (i < n) ? a[i] : 0; tot += v[k]; }
    __shared__ int sc[256];
    sc[t] = tot;
    __syncthreads();
    for (int off = 1; off < 256; off <<= 1) {
        int x = (t >= off) ? sc[t - off] : 0;
        __syncthreads();
        sc[t] += x;
        __syncthreads();
    }
    int excl = bsum[blockIdx.x] + sc[t] - tot;
#pragma unroll
    for (int k = 0; k < 8; ++k) { int i = base + k; if (i < n) a[i] = excl; excl += v[k]; }
    if (blockIdx.x == 0 && t == 0) a[n] = nE;
}

// ---------------------------------------------------------------------------
// Tiny scan of the 8+8 bucket counts -> exclusive offsets into cur_mb/cur_ub.
__global__ void bucket_scan_kernel(const int* __restrict__ cnt_mb,
                                   const int* __restrict__ cnt_ub,
                                   int* __restrict__ cur_mb, int* __restrict__ cur_ub) {
    if (threadIdx.x == 0 && blockIdx.x == 0) {
        int acc = 0;
        for (int b = 0; b < MBK; ++b) { cur_mb[b] = acc; acc += cnt_mb[b]; }
        acc = 0;
        for (int b = 0; b < MBK; ++b) { cur_ub[b] = acc; acc += cnt_ub[b]; }
    }
}

// ---------------------------------------------------------------------------
// Wave-compacted append of 4 edges/lane into one bucket's pair stream.
__device__ __forceinline__ void bucket_append(const int* bm, const unsigned* pm,
                                              int lane, int* __restrict__ cur,
                                              unsigned* __restrict__ out) {
#pragma unroll
    for (int b = 0; b < MBK; ++b) {
        unsigned long long mk[4];
        int ck[4];
        unsigned long long any = 0;
#pragma unroll
        for (int k = 0; k < 4; ++k) {
            mk[k] = __ballot(bm[k] == b);
            any |= mk[k];
            ck[k] = __popcll(mk[k]);
        }
        if (any) {
            const int leader = __ffsll((unsigned long long)any) - 1;
            int base = 0;
            if (lane == leader) base = atomicAdd(&cur[b], ck[0] + ck[1] + ck[2] + ck[3]);
            base = __shfl(base, leader);
            const unsigned long long lt = (1ull << lane) - 1ull;
            int pre = 0;
#pragma unroll
            for (int k = 0; k < 4; ++k) {
                if (bm[k] == b) out[base + pre + __popcll(mk[k] & lt)] = pm[k];
                pre += ck[k];
            }
        }
    }
}

// Level-1 scatter: pack (dlocal, src) into 4B, append grouped by 8 buckets,
// both directions, 4 edges per lane (128B contiguous chunks per append).
__global__ void bucket_scatter_kernel(const void* __restrict__ es,
                                      const void* __restrict__ ed,
                                      const int* __restrict__ flag,
                                      int* __restrict__ cur_mb, int* __restrict__ cur_ub,
                                      unsigned* __restrict__ pr_m,
                                      unsigned* __restrict__ pr_u, int nE) {
    const int is64 = *flag;
    const int lane = threadIdx.x & 63;
    const int wid  = (blockIdx.x * blockDim.x + threadIdx.x) >> 6;
    const int wpg  = (gridDim.x * blockDim.x) >> 6;
    for (long long wbase = (long long)wid * 256; wbase < nE; wbase += (long long)wpg * 256) {
        int bm[4], bu[4];
        unsigned pm[4], pu[4];
#pragma unroll
        for (int k = 0; k < 4; ++k) {
            const long long e = wbase + k * 64 + lane;
            if (e < nE) {
                const int s = load_idx(es, (int)e, is64);
                const int d = load_idx(ed, (int)e, is64);
                const int b0 = (unsigned)d / MB_M;
                const int b1 = (unsigned)s / MB_U;
                bm[k] = b0; pm[k] = ((unsigned)(d - b0 * MB_M) << 18) | (unsigned)s;
                bu[k] = b1; pu[k] = ((unsigned)(s - b1 * MB_U) << 17) | (unsigned)d;
            } else {
                bm[k] = -1; bu[k] = -1; pm[k] = 0; pu[k] = 0;
            }
        }
        bucket_append(bm, pm, lane, cur_mb, pr_m);
        bucket_append(bu, pu, lane, cur_ub, pr_u);
    }
}

// ---------------------------------------------------------------------------
// Level-2: scatter bucket-grouped pairs to exact per-node adj slots. Writes
// cluster inside a ~1MB rolling window (one bucket) -> L2-coalesced lines.
// bend = bucket END offsets (cur_* advanced by bucket_scatter).
__global__ void pair_fill_kernel(const unsigned* __restrict__ pr,
                                 const int* __restrict__ bend,
                                 int* __restrict__ cur, int* __restrict__ adj,
                                 int shift, int bspan, int nE) {
    int e0, e1, e2, e3, e4, e5, e6;
    e0 = bend[0]; e1 = bend[1]; e2 = bend[2]; e3 = bend[3];
    e4 = bend[4]; e5 = bend[5]; e6 = bend[6];
    const unsigned mask = (1u << shift) - 1u;
    const int stride = gridDim.x * blockDim.x;
    for (int i = blockIdx.x * blockDim.x + threadIdx.x; i < nE; i += stride) {
        const unsigned w = pr[i];
        int b = (i >= e0) + (i >= e1) + (i >= e2) + (i >= e3)
              + (i >= e4) + (i >= e5) + (i >= e6);
        const int d = b * bspan + (int)(w >> shift);
        const int s = (int)(w & mask);
        adj[atomicAdd(&cur[d], 1)] = s;
    }
}

// ---------------------------------------------------------------------------
// Fused tile kernel: block = 256 threads = 4 waves, tile = 64 nodes.
// (unchanged from round 4 — see comments there)
template <int RELU>
__global__ __launch_bounds__(256) void
fused_tile_kernel(const float* __restrict__ xsrc,
                  const float* __restrict__ xdst,
                  const int* __restrict__ rowptr,
                  const int* __restrict__ adj,
                  const float* __restrict__ Wl,
                  const float* __restrict__ Wr,
                  const float* __restrict__ bl,
                  float* __restrict__ out, int n) {
    __shared__ float sAX[128 * 64];  // row k, col = swizzled node
    __shared__ float sW[128 * 64];   // rows 0..63 = Wl[k][:], 64..127 = Wr[k][:]

    const int tid = threadIdx.x;
    {
        const float4* wl4 = (const float4*)Wl;
        const float4* wr4 = (const float4*)Wr;
        float4* sw4 = (float4*)sW;
#pragma unroll
        for (int i = 0; i < 4; ++i) {
            sw4[tid + 256 * i] = wl4[tid + 256 * i];
            sw4[1024 + tid + 256 * i] = wr4[tid + 256 * i];
        }
    }

    const int lane = tid & 63;
    const int w    = tid >> 6;      // wave 0..3
    const int grp  = lane >> 4;     // neighbor slot 0..3
    const int col  = lane & 15;     // float4 quarter 0..15
    const int base = blockIdx.x * 64;

    for (int s = 0; s < 16; ++s) {
        const int ln = w * 16 + s;   // local node 0..63
        const int i  = base + ln;
        if (i < n) {
            const int r0 = rowptr[i], r1 = rowptr[i + 1];
            float4 acc = make_float4(0.f, 0.f, 0.f, 0.f);
#pragma unroll 2
            for (int j = r0 + grp; j < r1; j += 4) {
                const int sv = adj[j];
                const float4 v = ((const float4*)(xsrc + (size_t)sv * DIM))[col];
                acc.x += v.x; acc.y += v.y; acc.z += v.z; acc.w += v.w;
            }
            acc.x += __shfl_xor(acc.x, 16); acc.y += __shfl_xor(acc.y, 16);
            acc.z += __shfl_xor(acc.z, 16); acc.w += __shfl_xor(acc.w, 16);
            acc.x += __shfl_xor(acc.x, 32); acc.y += __shfl_xor(acc.y, 32);
            acc.z += __shfl_xor(acc.z, 32); acc.w += __shfl_xor(acc.w, 32);
            const int pc = ((((ln >> 2) ^ col) << 2) | (ln & 3));
            if (grp == 0) {
                const float invd = 1.0f / fmaxf((float)(r1 - r0), 1.0f);
                sAX[(4 * col + 0) * 64 + pc] = acc.x * invd;
                sAX[(4 * col + 1) * 64 + pc] = acc.y * invd;
                sAX[(4 * col + 2) * 64 + pc] = acc.z * invd;
                sAX[(4 * col + 3) * 64 + pc] = acc.w * invd;
            } else if (grp == 1) {
                const float4 xv = ((const float4*)(xdst + (size_t)i * DIM))[col];
                sAX[(64 + 4 * col + 0) * 64 + pc] = xv.x;
                sAX[(64 + 4 * col + 1) * 64 + pc] = xv.y;
                sAX[(64 + 4 * col + 2) * 64 + pc] = xv.z;
                sAX[(64 + 4 * col + 3) * 64 + pc] = xv.w;
            }
        }
    }
    __syncthreads();

    // ---- transform ----
    const int rq = tid >> 4;   // node quad 0..15
    const int cq = tid & 15;   // dim quad 0..15
    const float4 bv = ((const float4*)bl)[cq];
    float4 a0 = bv, a1 = bv, a2 = bv, a3 = bv;
#pragma unroll 4
    for (int k = 0; k < 128; ++k) {
        const int g = (k >> 2) & 15;
        const float4 av = *(const float4*)&sAX[k * 64 + ((rq ^ g) << 2)];
        const float4 wv = *(const float4*)&sW[k * 64 + (cq << 2)];
        a0.x += av.x * wv.x; a0.y += av.x * wv.y; a0.z += av.x * wv.z; a0.w += av.x * wv.w;
        a1.x += av.y * wv.x; a1.y += av.y * wv.y; a1.z += av.y * wv.z; a1.w += av.y * wv.w;
        a2.x += av.z * wv.x; a2.y += av.z * wv.y; a2.z += av.z * wv.z; a2.w += av.z * wv.w;
        a3.x += av.w * wv.x; a3.y += av.w * wv.y; a3.z += av.w * wv.z; a3.w += av.w * wv.w;
    }
    float4 r[4] = {a0, a1, a2, a3};
#pragma unroll
    for (int i = 0; i < 4; ++i) {
        const int node = base + 4 * rq + i;
        if (node < n) {
            float4 v = r[i];
            if (RELU) {
                v.x = fmaxf(v.x, 0.f); v.y = fmaxf(v.y, 0.f);
                v.z = fmaxf(v.z, 0.f); v.w = fmaxf(v.w, 0.f);
            }
            ((float4*)(out + (size_t)node * DIM))[cq] = v;
        }
    }
}

// ---------------------------------------------------------------------------
extern "C" void kernel_launch(void* const* d_in, const int* in_sizes, int n_in,
                              void* d_out, int out_size, void* d_ws, size_t ws_size,
                              hipStream_t stream) {
    const float* x_user  = (const float*)d_in[0];
    const float* x_movie = (const float*)d_in[1];
    const void*  e_src   = d_in[2];
    const void*  e_dst   = d_in[3];
    const float* W1_um_l = (const float*)d_in[4];
    const float* W1_um_r = (const float*)d_in[5];
    const float* W1_mu_l = (const float*)d_in[6];
    const float* W1_mu_r = (const float*)d_in[7];
    const float* W2_um_l = (const float*)d_in[8];
    const float* W2_um_r = (const float*)d_in[9];
    const float* W2_mu_l = (const float*)d_in[10];
    const float* W2_mu_r = (const float*)d_in[11];
    const float* b1_um = (const float*)d_in[12];
    const float* b1_mu = (const float*)d_in[13];
    const float* b2_um = (const float*)d_in[14];
    const float* b2_mu = (const float*)d_in[15];
    const int nE = in_sizes[2];

    // workspace carve-up (256B aligned)
    char* ws = (char*)d_ws;
    size_t off = 0;
    auto carve = [&](size_t bytes) {
        void* p = ws + off;
        off += (bytes + 255) & ~(size_t)255;
        return p;
    };
    int*      flag   = (int*)carve(4);
    int*      rp_u   = (int*)carve(((size_t)NU + 1) * 4);
    int*      rp_m   = (int*)carve(((size_t)NM + 1) * 4);
    int*      cur_u  = (int*)carve((size_t)NU * 4);
    int*      cur_m  = (int*)carve((size_t)NM * 4);
    int*      bsum_u = (int*)carve(128 * 4);
    int*      bsum_m = (int*)carve(128 * 4);
    int*      cnt_mb = (int*)carve(MBK * 4);
    int*      cnt_ub = (int*)carve(MBK * 4);
    int*      cur_mb = (int*)carve(MBK * 4);
    int*      cur_ub = (int*)carve(MBK * 4);
    int*      adj_u  = (int*)carve((size_t)nE * 4);
    int*      adj_m  = (int*)carve((size_t)nE * 4);
    unsigned* pr_m   = (unsigned*)carve((size_t)nE * 4);
    unsigned* pr_u   = (unsigned*)carve((size_t)nE * 4);
    float*    m1     = (float*)carve((size_t)NM * DIM * 4);

    float* u2 = (float*)d_out;                    // [NU,64]; also u1 (in-place)
    float* m2 = (float*)d_out + (size_t)NU * DIM; // [NM,64]
    float* u1 = u2;

    // ---- build CSR (both directions) via hierarchical binning ----
    hipMemsetAsync(rp_u, 0, ((size_t)NU + 1) * 4, stream);
    hipMemsetAsync(rp_m, 0, ((size_t)NM + 1) * 4, stream);
    hipMemsetAsync(cnt_mb, 0, MBK * 4, stream);
    hipMemsetAsync(cnt_ub, 0, MBK * 4, stream);
    detect_idx_kernel<<<1, 256, 0, stream>>>((const unsigned int*)e_src, flag);

    const int EB = 2048;
    count_kernel<<<EB, 256, 0, stream>>>(e_src, e_dst, flag, rp_u, rp_m,
                                         cnt_mb, cnt_ub, nE);

    const int nbU = (NU + SCAN_CHUNK - 1) / SCAN_CHUNK;
    const int nbM = (NM + SCAN_CHUNK - 1) / SCAN_CHUNK;
    scan_block_sums<<<nbU, 256, 0, stream>>>(rp_u, bsum_u, NU);
    scan_block_sums<<<nbM, 256, 0, stream>>>(rp_m, bsum_m, NM);
    scan_bsum<<<1, 64, 0, stream>>>(bsum_u, nbU);
    scan_bsum<<<1, 64, 0, stream>>>(bsum_m, nbM);
    scan_apply<<<nbU, 256, 0, stream>>>(rp_u, bsum_u, NU, nE);
    scan_apply<<<nbM, 256, 0, stream>>>(rp_m, bsum_m, NM, nE);
    bucket_scan_kernel<<<1, 64, 0, stream>>>(cnt_mb, cnt_ub, cur_mb, cur_ub);

    hipMemcpyAsync(cur_u, rp_u, (size_t)NU * 4, hipMemcpyDeviceToDevice, stream);
    hipMemcpyAsync(cur_m, rp_m, (size_t)NM * 4, hipMemcpyDeviceToDevice, stream);

    // level-1: bucket-grouped packed pairs (streaming writes)
    bucket_scatter_kernel<<<1024, 256, 0, stream>>>(e_src, e_dst, flag,
                                                    cur_mb, cur_ub, pr_m, pr_u, nE);
    // level-2: windowed scatter to exact adj slots (cur_mb/ub now = bucket ends)
    pair_fill_kernel<<<1024, 256, 0, stream>>>(pr_m, cur_mb, cur_m, adj_m,
                                               18, MB_M, nE);
    pair_fill_kernel<<<1024, 256, 0, stream>>>(pr_u, cur_ub, cur_u, adj_u,
                                               17, MB_U, nE);

    // ---- fused layers ----
    const int nbm = (NM + 63) / 64;
    const int nbu = (NU + 63) / 64;
    fused_tile_kernel<1><<<nbm, 256, 0, stream>>>(x_user,  x_movie, rp_m, adj_m,
                                                  W1_um_l, W1_um_r, b1_um, m1, NM);
    fused_tile_kernel<1><<<nbu, 256, 0, stream>>>(x_movie, x_user,  rp_u, adj_u,
                                                  W1_mu_l, W1_mu_r, b1_mu, u1, NU);
    fused_tile_kernel<0><<<nbm, 256, 0, stream>>>(u1, m1, rp_m, adj_m,
                                                  W2_um_l, W2_um_r, b2_um, m2, NM);
    fused_tile_kernel<0><<<nbu, 256, 0, stream>>>(m1, u1, rp_u, adj_u,
                                                  W2_mu_l, W2_mu_r, b2_mu, u2, NU);
}

// Round 6
// 1360.597 us; speedup vs baseline: 1.7952x; 1.7952x over previous
//
#include <hip/hip_runtime.h>
#include <stdint.h>

#define NU 200000
#define NM 100000
#define DIM 64
#define SCAN_CHUNK 2048
#define MBK 8            // mega-buckets per direction
#define MB_M 12500       // movie node span per bucket (NM/8)
#define MB_U 25000       // user  node span per bucket (NU/8)
#define G_SC 1024        // blocks for count/pair_scatter (fixed chunk assignment)

// ---------------------------------------------------------------------------
// Detect whether edge index arrays are int64 or int32.
__global__ void detect_idx_kernel(const unsigned int* __restrict__ words,
                                  int* __restrict__ flag) {
    __shared__ int nz;
    if (threadIdx.x == 0) nz = 0;
    __syncthreads();
    for (int i = threadIdx.x; i < 2048; i += blockDim.x)
        if (words[2 * i + 1] != 0u) nz = 1;
    __syncthreads();
    if (threadIdx.x == 0) *flag = (nz == 0) ? 1 : 0;   // 1 => int64
}

__device__ __forceinline__ int load_idx(const void* __restrict__ p, int e, int is64) {
    if (is64) return (int)((const long long*)p)[e];
    return ((const int*)p)[e];
}

// ---------------------------------------------------------------------------
// Degree histogram (per node, both directions) + per-block 8-bucket histogram
// (bucket-major layout hist[b*G_SC + blk]) with FIXED per-block edge chunks so
// pair_scatter_kernel can reproduce the assignment deterministically.
__global__ void count_kernel(const void* __restrict__ es, const void* __restrict__ ed,
                             const int* __restrict__ flag,
                             int* __restrict__ deg_u, int* __restrict__ deg_m,
                             int* __restrict__ hist_m, int* __restrict__ hist_u,
                             int nE, int cpb) {
    __shared__ int h[2 * MBK];
    if (threadIdx.x < 2 * MBK) h[threadIdx.x] = 0;
    __syncthreads();
    const int is64 = *flag;
    const int e0 = blockIdx.x * cpb;
    const int e1 = min(nE, e0 + cpb);
    for (int e = e0 + threadIdx.x; e < e1; e += blockDim.x) {
        int s = load_idx(es, e, is64);
        int d = load_idx(ed, e, is64);
        atomicAdd(&deg_u[s], 1);
        atomicAdd(&deg_m[d], 1);
        atomicAdd(&h[(unsigned)d / MB_M], 1);
        atomicAdd(&h[MBK + (unsigned)s / MB_U], 1);
    }
    __syncthreads();
    if (threadIdx.x < MBK)
        hist_m[threadIdx.x * G_SC + blockIdx.x] = h[threadIdx.x];
    else if (threadIdx.x < 2 * MBK)
        hist_u[(threadIdx.x - MBK) * G_SC + blockIdx.x] = h[threadIdx.x];
}

// ---------------------------------------------------------------------------
// Exclusive scan over n ints, 3 phases (chunk = 2048 = 256 thr x 8).
__global__ void scan_block_sums(const int* __restrict__ a, int* __restrict__ bsum, int n) {
    int base = blockIdx.x * SCAN_CHUNK + threadIdx.x * 8;
    int tot = 0;
#pragma unroll
    for (int k = 0; k < 8; ++k) { int i = base + k; if (i < n) tot += a[i]; }
    __shared__ int sc[256];
    sc[threadIdx.x] = tot;
    __syncthreads();
    for (int off = 128; off > 0; off >>= 1) {
        if (threadIdx.x < off) sc[threadIdx.x] += sc[threadIdx.x + off];
        __syncthreads();
    }
    if (threadIdx.x == 0) bsum[blockIdx.x] = sc[0];
}

__global__ void scan_bsum(int* __restrict__ bsum, int nb) {
    if (blockIdx.x == 0 && threadIdx.x == 0) {
        int acc = 0;
        for (int i = 0; i < nb; ++i) { int v = bsum[i]; bsum[i] = acc; acc += v; }
    }
}

__global__ void scan_apply(int* __restrict__ a, const int* __restrict__ bsum, int n, int nE) {
    const int t = threadIdx.x;
    int base = blockIdx.x * SCAN_CHUNK + t * 8;
    int v[8];
    int tot = 0;
#pragma unroll
    for (int k = 0; k < 8; ++k) { int i = base + k; v[k] = (i < n) ? a[i] : 0; tot += v[k]; }
    __shared__ int sc[256];
    sc[t] = tot;
    __syncthreads();
    for (int off = 1; off < 256; off <<= 1) {
        int x = (t >= off) ? sc[t - off] : 0;
        __syncthreads();
        sc[t] += x;
        __syncthreads();
    }
    int excl = bsum[blockIdx.x] + sc[t] - tot;
#pragma unroll
    for (int k = 0; k < 8; ++k) { int i = base + k; if (i < n) a[i] = excl; excl += v[k]; }
    if (blockIdx.x == 0 && t == 0) a[n] = nE;
}

// ---------------------------------------------------------------------------
// Exclusive scan of one direction's per-block bucket histogram (8*G_SC ints,
// bucket-major) in place; also emits the 8 bucket END offsets. 2 blocks: 0->m.
__global__ void hist_scan_kernel(int* __restrict__ hist_m, int* __restrict__ hist_u,
                                 int* __restrict__ bend_m, int* __restrict__ bend_u,
                                 int nE) {
    int* hist = (blockIdx.x == 0) ? hist_m : hist_u;
    int* bend = (blockIdx.x == 0) ? bend_m : bend_u;
    const int t = threadIdx.x;          // 256 threads x 32 = 8192 = 8*G_SC
    const int base = t * 32;
    int v[32];
    int tot = 0;
#pragma unroll
    for (int k = 0; k < 32; ++k) { v[k] = hist[base + k]; tot += v[k]; }
    __shared__ int sc[256];
    sc[t] = tot;
    __syncthreads();
    for (int off = 1; off < 256; off <<= 1) {
        int x = (t >= off) ? sc[t - off] : 0;
        __syncthreads();
        sc[t] += x;
        __syncthreads();
    }
    int excl = sc[t] - tot;
#pragma unroll
    for (int k = 0; k < 32; ++k) { int tmp = v[k]; hist[base + k] = excl; excl += tmp; }
    __syncthreads();
    if (t < MBK - 1) bend[t] = hist[(t + 1) * G_SC];
    else if (t == MBK - 1) bend[t] = nE;
}

// ---------------------------------------------------------------------------
// Level-1 scatter, deterministic: block re-reads its fixed edge chunk, reserves
// slots from 16 LDS cursors (init = scanned per-block offsets), writes packed
// (dlocal,src) pairs into its exclusive per-bucket chunks. NO global atomics.
__global__ void pair_scatter_kernel(const void* __restrict__ es,
                                    const void* __restrict__ ed,
                                    const int* __restrict__ flag,
                                    const int* __restrict__ hist_m,
                                    const int* __restrict__ hist_u,
                                    unsigned* __restrict__ pr_m,
                                    unsigned* __restrict__ pr_u,
                                    int nE, int cpb) {
    __shared__ int cur[2 * MBK];
    if (threadIdx.x < MBK)
        cur[threadIdx.x] = hist_m[threadIdx.x * G_SC + blockIdx.x];
    else if (threadIdx.x < 2 * MBK)
        cur[threadIdx.x] = hist_u[(threadIdx.x - MBK) * G_SC + blockIdx.x];
    __syncthreads();
    const int is64 = *flag;
    const int e0 = blockIdx.x * cpb;
    const int e1 = min(nE, e0 + cpb);
    for (int e = e0 + threadIdx.x; e < e1; e += blockDim.x) {
        const int s = load_idx(es, e, is64);
        const int d = load_idx(ed, e, is64);
        const int b0 = (unsigned)d / MB_M;
        const int b1 = (unsigned)s / MB_U;
        const int p0 = atomicAdd(&cur[b0], 1);
        pr_m[p0] = ((unsigned)(d - b0 * MB_M) << 18) | (unsigned)s;
        const int p1 = atomicAdd(&cur[MBK + b1], 1);
        pr_u[p1] = ((unsigned)(s - b1 * MB_U) << 17) | (unsigned)d;
    }
}

// ---------------------------------------------------------------------------
// Level-2: scatter bucket-grouped pairs to exact per-node adj slots. Writes
// cluster inside a ~1MB rolling window (one bucket) -> L2-coalesced lines.
__global__ void pair_fill_kernel(const unsigned* __restrict__ pr,
                                 const int* __restrict__ bend,
                                 int* __restrict__ cur, int* __restrict__ adj,
                                 int shift, int bspan, int nE) {
    int e0, e1, e2, e3, e4, e5, e6;
    e0 = bend[0]; e1 = bend[1]; e2 = bend[2]; e3 = bend[3];
    e4 = bend[4]; e5 = bend[5]; e6 = bend[6];
    const unsigned mask = (1u << shift) - 1u;
    const int stride = gridDim.x * blockDim.x;
    for (int i = blockIdx.x * blockDim.x + threadIdx.x; i < nE; i += stride) {
        const unsigned w = pr[i];
        int b = (i >= e0) + (i >= e1) + (i >= e2) + (i >= e3)
              + (i >= e4) + (i >= e5) + (i >= e6);
        const int d = b * bspan + (int)(w >> shift);
        const int s = (int)(w & mask);
        adj[atomicAdd(&cur[d], 1)] = s;
    }
}

// ---------------------------------------------------------------------------
// Fused tile kernel: block = 256 threads = 4 waves, tile = 64 nodes.
// (see round-4 comments; unchanged)
template <int RELU>
__global__ __launch_bounds__(256) void
fused_tile_kernel(const float* __restrict__ xsrc,
                  const float* __restrict__ xdst,
                  const int* __restrict__ rowptr,
                  const int* __restrict__ adj,
                  const float* __restrict__ Wl,
                  const float* __restrict__ Wr,
                  const float* __restrict__ bl,
                  float* __restrict__ out, int n) {
    __shared__ float sAX[128 * 64];  // row k, col = swizzled node
    __shared__ float sW[128 * 64];   // rows 0..63 = Wl[k][:], 64..127 = Wr[k][:]

    const int tid = threadIdx.x;
    {
        const float4* wl4 = (const float4*)Wl;
        const float4* wr4 = (const float4*)Wr;
        float4* sw4 = (float4*)sW;
#pragma unroll
        for (int i = 0; i < 4; ++i) {
            sw4[tid + 256 * i] = wl4[tid + 256 * i];
            sw4[1024 + tid + 256 * i] = wr4[tid + 256 * i];
        }
    }

    const int lane = tid & 63;
    const int w    = tid >> 6;      // wave 0..3
    const int grp  = lane >> 4;     // neighbor slot 0..3
    const int col  = lane & 15;     // float4 quarter 0..15
    const int base = blockIdx.x * 64;

    for (int s = 0; s < 16; ++s) {
        const int ln = w * 16 + s;   // local node 0..63
        const int i  = base + ln;
        if (i < n) {
            const int r0 = rowptr[i], r1 = rowptr[i + 1];
            float4 acc = make_float4(0.f, 0.f, 0.f, 0.f);
#pragma unroll 2
            for (int j = r0 + grp; j < r1; j += 4) {
                const int sv = adj[j];
                const float4 v = ((const float4*)(xsrc + (size_t)sv * DIM))[col];
                acc.x += v.x; acc.y += v.y; acc.z += v.z; acc.w += v.w;
            }
            acc.x += __shfl_xor(acc.x, 16); acc.y += __shfl_xor(acc.y, 16);
            acc.z += __shfl_xor(acc.z, 16); acc.w += __shfl_xor(acc.w, 16);
            acc.x += __shfl_xor(acc.x, 32); acc.y += __shfl_xor(acc.y, 32);
            acc.z += __shfl_xor(acc.z, 32); acc.w += __shfl_xor(acc.w, 32);
            const int pc = ((((ln >> 2) ^ col) << 2) | (ln & 3));
            if (grp == 0) {
                const float invd = 1.0f / fmaxf((float)(r1 - r0), 1.0f);
                sAX[(4 * col + 0) * 64 + pc] = acc.x * invd;
                sAX[(4 * col + 1) * 64 + pc] = acc.y * invd;
                sAX[(4 * col + 2) * 64 + pc] = acc.z * invd;
                sAX[(4 * col + 3) * 64 + pc] = acc.w * invd;
            } else if (grp == 1) {
                const float4 xv = ((const float4*)(xdst + (size_t)i * DIM))[col];
                sAX[(64 + 4 * col + 0) * 64 + pc] = xv.x;
                sAX[(64 + 4 * col + 1) * 64 + pc] = xv.y;
                sAX[(64 + 4 * col + 2) * 64 + pc] = xv.z;
                sAX[(64 + 4 * col + 3) * 64 + pc] = xv.w;
            }
        }
    }
    __syncthreads();

    // ---- transform ----
    const int rq = tid >> 4;   // node quad 0..15
    const int cq = tid & 15;   // dim quad 0..15
    const float4 bv = ((const float4*)bl)[cq];
    float4 a0 = bv, a1 = bv, a2 = bv, a3 = bv;
#pragma unroll 4
    for (int k = 0; k < 128; ++k) {
        const int g = (k >> 2) & 15;
        const float4 av = *(const float4*)&sAX[k * 64 + ((rq ^ g) << 2)];
        const float4 wv = *(const float4*)&sW[k * 64 + (cq << 2)];
        a0.x += av.x * wv.x; a0.y += av.x * wv.y; a0.z += av.x * wv.z; a0.w += av.x * wv.w;
        a1.x += av.y * wv.x; a1.y += av.y * wv.y; a1.z += av.y * wv.z; a1.w += av.y * wv.w;
        a2.x += av.z * wv.x; a2.y += av.z * wv.y; a2.z += av.z * wv.z; a2.w += av.z * wv.w;
        a3.x += av.w * wv.x; a3.y += av.w * wv.y; a3.z += av.w * wv.z; a3.w += av.w * wv.w;
    }
    float4 r[4] = {a0, a1, a2, a3};
#pragma unroll
    for (int i = 0; i < 4; ++i) {
        const int node = base + 4 * rq + i;
        if (node < n) {
            float4 v = r[i];
            if (RELU) {
                v.x = fmaxf(v.x, 0.f); v.y = fmaxf(v.y, 0.f);
                v.z = fmaxf(v.z, 0.f); v.w = fmaxf(v.w, 0.f);
            }
            ((float4*)(out + (size_t)node * DIM))[cq] = v;
        }
    }
}

// ---------------------------------------------------------------------------
extern "C" void kernel_launch(void* const* d_in, const int* in_sizes, int n_in,
                              void* d_out, int out_size, void* d_ws, size_t ws_size,
                              hipStream_t stream) {
    const float* x_user  = (const float*)d_in[0];
    const float* x_movie = (const float*)d_in[1];
    const void*  e_src   = d_in[2];
    const void*  e_dst   = d_in[3];
    const float* W1_um_l = (const float*)d_in[4];
    const float* W1_um_r = (const float*)d_in[5];
    const float* W1_mu_l = (const float*)d_in[6];
    const float* W1_mu_r = (const float*)d_in[7];
    const float* W2_um_l = (const float*)d_in[8];
    const float* W2_um_r = (const float*)d_in[9];
    const float* W2_mu_l = (const float*)d_in[10];
    const float* W2_mu_r = (const float*)d_in[11];
    const float* b1_um = (const float*)d_in[12];
    const float* b1_mu = (const float*)d_in[13];
    const float* b2_um = (const float*)d_in[14];
    const float* b2_mu = (const float*)d_in[15];
    const int nE = in_sizes[2];
    const int cpb = (nE + G_SC - 1) / G_SC;

    // workspace carve-up (256B aligned)
    char* ws = (char*)d_ws;
    size_t off = 0;
    auto carve = [&](size_t bytes) {
        void* p = ws + off;
        off += (bytes + 255) & ~(size_t)255;
        return p;
    };
    int*      flag   = (int*)carve(4);
    int*      rp_u   = (int*)carve(((size_t)NU + 1) * 4);
    int*      rp_m   = (int*)carve(((size_t)NM + 1) * 4);
    int*      cur_u  = (int*)carve((size_t)NU * 4);
    int*      cur_m  = (int*)carve((size_t)NM * 4);
    int*      bsum_u = (int*)carve(128 * 4);
    int*      bsum_m = (int*)carve(128 * 4);
    int*      hist_m = (int*)carve((size_t)MBK * G_SC * 4);
    int*      hist_u = (int*)carve((size_t)MBK * G_SC * 4);
    int*      bend_m = (int*)carve(MBK * 4);
    int*      bend_u = (int*)carve(MBK * 4);
    int*      adj_u  = (int*)carve((size_t)nE * 4);
    int*      adj_m  = (int*)carve((size_t)nE * 4);
    unsigned* pr_m   = (unsigned*)carve((size_t)nE * 4);
    unsigned* pr_u   = (unsigned*)carve((size_t)nE * 4);
    float*    m1     = (float*)carve((size_t)NM * DIM * 4);

    float* u2 = (float*)d_out;                    // [NU,64]; also u1 (in-place)
    float* m2 = (float*)d_out + (size_t)NU * DIM; // [NM,64]
    float* u1 = u2;

    // ---- build CSR (both directions) via deterministic two-level binning ----
    hipMemsetAsync(rp_u, 0, ((size_t)NU + 1) * 4, stream);
    hipMemsetAsync(rp_m, 0, ((size_t)NM + 1) * 4, stream);
    detect_idx_kernel<<<1, 256, 0, stream>>>((const unsigned int*)e_src, flag);

    count_kernel<<<G_SC, 256, 0, stream>>>(e_src, e_dst, flag, rp_u, rp_m,
                                           hist_m, hist_u, nE, cpb);

    const int nbU = (NU + SCAN_CHUNK - 1) / SCAN_CHUNK;
    const int nbM = (NM + SCAN_CHUNK - 1) / SCAN_CHUNK;
    scan_block_sums<<<nbU, 256, 0, stream>>>(rp_u, bsum_u, NU);
    scan_block_sums<<<nbM, 256, 0, stream>>>(rp_m, bsum_m, NM);
    scan_bsum<<<1, 64, 0, stream>>>(bsum_u, nbU);
    scan_bsum<<<1, 64, 0, stream>>>(bsum_m, nbM);
    scan_apply<<<nbU, 256, 0, stream>>>(rp_u, bsum_u, NU, nE);
    scan_apply<<<nbM, 256, 0, stream>>>(rp_m, bsum_m, NM, nE);
    hist_scan_kernel<<<2, 256, 0, stream>>>(hist_m, hist_u, bend_m, bend_u, nE);

    hipMemcpyAsync(cur_u, rp_u, (size_t)NU * 4, hipMemcpyDeviceToDevice, stream);
    hipMemcpyAsync(cur_m, rp_m, (size_t)NM * 4, hipMemcpyDeviceToDevice, stream);

    // level-1: deterministic bucket-grouped packed pairs (LDS cursors only)
    pair_scatter_kernel<<<G_SC, 256, 0, stream>>>(e_src, e_dst, flag,
                                                  hist_m, hist_u, pr_m, pr_u,
                                                  nE, cpb);
    // level-2: windowed scatter to exact adj slots
    pair_fill_kernel<<<1024, 256, 0, stream>>>(pr_m, bend_m, cur_m, adj_m,
                                               18, MB_M, nE);
    pair_fill_kernel<<<1024, 256, 0, stream>>>(pr_u, bend_u, cur_u, adj_u,
                                               17, MB_U, nE);

    // ---- fused layers ----
    const int nbm = (NM + 63) / 64;
    const int nbu = (NU + 63) / 64;
    fused_tile_kernel<1><<<nbm, 256, 0, stream>>>(x_user,  x_movie, rp_m, adj_m,
                                                  W1_um_l, W1_um_r, b1_um, m1, NM);
    fused_tile_kernel<1><<<nbu, 256, 0, stream>>>(x_movie, x_user,  rp_u, adj_u,
                                                  W1_mu_l, W1_mu_r, b1_mu, u1, NU);
    fused_tile_kernel<0><<<nbm, 256, 0, stream>>>(u1, m1, rp_m, adj_m,
                                                  W2_um_l, W2_um_r, b2_um, m2, NM);
    fused_tile_kernel<0><<<nbu, 256, 0, stream>>>(m1, u1, rp_u, adj_u,
                                                  W2_mu_l, W2_mu_r, b2_mu, u2, NU);
}

// Round 7
// 931.493 us; speedup vs baseline: 2.6221x; 1.4607x over previous
//
#include <hip/hip_runtime.h>
#include <stdint.h>

#define NU 200000
#define NM 100000
#define DIM 64
#define UCH 100000       // user-direction chunk (agg buffer sized for 100k nodes)
#define SCAN_CHUNK 2048
#define MBK 8            // mega-buckets per direction
#define MB_M 12500       // movie node span per bucket (NM/8)
#define MB_U 25000       // user  node span per bucket (NU/8)
#define G_SC 1024        // blocks for count/pair_scatter (fixed chunk assignment)

// ---------------------------------------------------------------------------
// Detect whether edge index arrays are int64 or int32.
__global__ void detect_idx_kernel(const unsigned int* __restrict__ words,
                                  int* __restrict__ flag) {
    __shared__ int nz;
    if (threadIdx.x == 0) nz = 0;
    __syncthreads();
    for (int i = threadIdx.x; i < 2048; i += blockDim.x)
        if (words[2 * i + 1] != 0u) nz = 1;
    __syncthreads();
    if (threadIdx.x == 0) *flag = (nz == 0) ? 1 : 0;   // 1 => int64
}

__device__ __forceinline__ int load_idx(const void* __restrict__ p, int e, int is64) {
    if (is64) return (int)((const long long*)p)[e];
    return ((const int*)p)[e];
}

// ---------------------------------------------------------------------------
// Degree histogram (per node, both directions) + per-block 8-bucket histogram
// (bucket-major hist[b*G_SC + blk]) with FIXED per-block edge chunks so
// pair_scatter_kernel can reproduce the assignment deterministically.
__global__ void count_kernel(const void* __restrict__ es, const void* __restrict__ ed,
                             const int* __restrict__ flag,
                             int* __restrict__ deg_u, int* __restrict__ deg_m,
                             int* __restrict__ hist_m, int* __restrict__ hist_u,
                             int nE, int cpb) {
    __shared__ int h[2 * MBK];
    if (threadIdx.x < 2 * MBK) h[threadIdx.x] = 0;
    __syncthreads();
    const int is64 = *flag;
    const int e0 = blockIdx.x * cpb;
    const int e1 = min(nE, e0 + cpb);
    for (int e = e0 + threadIdx.x; e < e1; e += blockDim.x) {
        int s = load_idx(es, e, is64);
        int d = load_idx(ed, e, is64);
        atomicAdd(&deg_u[s], 1);
        atomicAdd(&deg_m[d], 1);
        atomicAdd(&h[(unsigned)d / MB_M], 1);
        atomicAdd(&h[MBK + (unsigned)s / MB_U], 1);
    }
    __syncthreads();
    if (threadIdx.x < MBK)
        hist_m[threadIdx.x * G_SC + blockIdx.x] = h[threadIdx.x];
    else if (threadIdx.x < 2 * MBK)
        hist_u[(threadIdx.x - MBK) * G_SC + blockIdx.x] = h[threadIdx.x];
}

// ---------------------------------------------------------------------------
// Exclusive scan over n ints, 3 phases (chunk = 2048 = 256 thr x 8).
__global__ void scan_block_sums(const int* __restrict__ a, int* __restrict__ bsum, int n) {
    int base = blockIdx.x * SCAN_CHUNK + threadIdx.x * 8;
    int tot = 0;
#pragma unroll
    for (int k = 0; k < 8; ++k) { int i = base + k; if (i < n) tot += a[i]; }
    __shared__ int sc[256];
    sc[threadIdx.x] = tot;
    __syncthreads();
    for (int off = 128; off > 0; off >>= 1) {
        if (threadIdx.x < off) sc[threadIdx.x] += sc[threadIdx.x + off];
        __syncthreads();
    }
    if (threadIdx.x == 0) bsum[blockIdx.x] = sc[0];
}

__global__ void scan_bsum(int* __restrict__ bsum, int nb) {
    if (blockIdx.x == 0 && threadIdx.x == 0) {
        int acc = 0;
        for (int i = 0; i < nb; ++i) { int v = bsum[i]; bsum[i] = acc; acc += v; }
    }
}

__global__ void scan_apply(int* __restrict__ a, const int* __restrict__ bsum, int n, int nE) {
    const int t = threadIdx.x;
    int base = blockIdx.x * SCAN_CHUNK + t * 8;
    int v[8];
    int tot = 0;
#pragma unroll
    for (int k = 0; k < 8; ++k) { int i = base + k; v[k] = (i < n) ? a[i] : 0; tot += v[k]; }
    __shared__ int sc[256];
    sc[t] = tot;
    __syncthreads();
    for (int off = 1; off < 256; off <<= 1) {
        int x = (t >= off) ? sc[t - off] : 0;
        __syncthreads();
        sc[t] += x;
        __syncthreads();
    }
    int excl = bsum[blockIdx.x] + sc[t] - tot;
#pragma unroll
    for (int k = 0; k < 8; ++k) { int i = base + k; if (i < n) a[i] = excl; excl += v[k]; }
    if (blockIdx.x == 0 && t == 0) a[n] = nE;
}

// ---------------------------------------------------------------------------
// Exclusive scan of one direction's per-block bucket histogram (8*G_SC ints,
// bucket-major) in place; also emits the 8 bucket END offsets. 2 blocks.
__global__ void hist_scan_kernel(int* __restrict__ hist_m, int* __restrict__ hist_u,
                                 int* __restrict__ bend_m, int* __restrict__ bend_u,
                                 int nE) {
    int* hist = (blockIdx.x == 0) ? hist_m : hist_u;
    int* bend = (blockIdx.x == 0) ? bend_m : bend_u;
    const int t = threadIdx.x;          // 256 threads x 32 = 8192 = 8*G_SC
    const int base = t * 32;
    int v[32];
    int tot = 0;
#pragma unroll
    for (int k = 0; k < 32; ++k) { v[k] = hist[base + k]; tot += v[k]; }
    __shared__ int sc[256];
    sc[t] = tot;
    __syncthreads();
    for (int off = 1; off < 256; off <<= 1) {
        int x = (t >= off) ? sc[t - off] : 0;
        __syncthreads();
        sc[t] += x;
        __syncthreads();
    }
    int excl = sc[t] - tot;
#pragma unroll
    for (int k = 0; k < 32; ++k) { int tmp = v[k]; hist[base + k] = excl; excl += tmp; }
    __syncthreads();
    if (t < MBK - 1) bend[t] = hist[(t + 1) * G_SC];
    else if (t == MBK - 1) bend[t] = nE;
}

// ---------------------------------------------------------------------------
// Level-1 scatter, deterministic: block re-reads its fixed edge chunk, reserves
// slots from 16 LDS cursors (init = scanned per-block offsets), writes packed
// (dlocal,src) pairs into its exclusive per-bucket chunks. NO global atomics.
__global__ void pair_scatter_kernel(const void* __restrict__ es,
                                    const void* __restrict__ ed,
                                    const int* __restrict__ flag,
                                    const int* __restrict__ hist_m,
                                    const int* __restrict__ hist_u,
                                    unsigned* __restrict__ pr_m,
                                    unsigned* __restrict__ pr_u,
                                    int nE, int cpb) {
    __shared__ int cur[2 * MBK];
    if (threadIdx.x < MBK)
        cur[threadIdx.x] = hist_m[threadIdx.x * G_SC + blockIdx.x];
    else if (threadIdx.x < 2 * MBK)
        cur[threadIdx.x] = hist_u[(threadIdx.x - MBK) * G_SC + blockIdx.x];
    __syncthreads();
    const int is64 = *flag;
    const int e0 = blockIdx.x * cpb;
    const int e1 = min(nE, e0 + cpb);
    for (int e = e0 + threadIdx.x; e < e1; e += blockDim.x) {
        const int s = load_idx(es, e, is64);
        const int d = load_idx(ed, e, is64);
        const int b0 = (unsigned)d / MB_M;
        const int b1 = (unsigned)s / MB_U;
        const int p0 = atomicAdd(&cur[b0], 1);
        pr_m[p0] = ((unsigned)(d - b0 * MB_M) << 18) | (unsigned)s;
        const int p1 = atomicAdd(&cur[MBK + b1], 1);
        pr_u[p1] = ((unsigned)(s - b1 * MB_U) << 17) | (unsigned)d;
    }
}

// ---------------------------------------------------------------------------
// Level-2: scatter bucket-grouped pairs to exact per-node adj slots. Writes
// cluster inside a ~1MB rolling window (one bucket) -> L2-coalesced lines.
__global__ void pair_fill_kernel(const unsigned* __restrict__ pr,
                                 const int* __restrict__ bend,
                                 int* __restrict__ cur, int* __restrict__ adj,
                                 int shift, int bspan, int nE) {
    int e0, e1, e2, e3, e4, e5, e6;
    e0 = bend[0]; e1 = bend[1]; e2 = bend[2]; e3 = bend[3];
    e4 = bend[4]; e5 = bend[5]; e6 = bend[6];
    const unsigned mask = (1u << shift) - 1u;
    const int stride = gridDim.x * blockDim.x;
    for (int i = blockIdx.x * blockDim.x + threadIdx.x; i < nE; i += stride) {
        const unsigned w = pr[i];
        int b = (i >= e0) + (i >= e1) + (i >= e2) + (i >= e3)
              + (i >= e4) + (i >= e5) + (i >= e6);
        const int d = b * bspan + (int)(w >> shift);
        const int s = (int)(w & mask);
        adj[atomicAdd(&cur[d], 1)] = s;
    }
}

// ---------------------------------------------------------------------------
// Mean-aggregate gather: no LDS, low VGPR -> high occupancy, high MLP.
// Wave layout: grp = lane>>4 (neighbor slot), col = lane&15 (float4 column).
// Two accumulators / 8 neighbors in flight per wave. One coalesced 256B
// streaming write per node (grp0). deg==0 -> writes zeros (no memset needed).
// agg is indexed RELATIVE to n0 (chunked buffer).
__global__ __launch_bounds__(256) void
gather_mean_kernel(const float* __restrict__ xsrc,
                   const int* __restrict__ rowptr,
                   const int* __restrict__ adj,
                   float* __restrict__ agg,
                   int n0, int n1) {
    const int lane = threadIdx.x & 63;
    const int grp  = lane >> 4;
    const int col  = lane & 15;
    const int wid  = (blockIdx.x * blockDim.x + threadIdx.x) >> 6;
    const int nw   = (gridDim.x * blockDim.x) >> 6;
    for (int i = n0 + wid; i < n1; i += nw) {
        const int r0 = rowptr[i], r1 = rowptr[i + 1];
        float ax = 0.f, ay = 0.f, az = 0.f, aw = 0.f;
        float bx = 0.f, by = 0.f, bz = 0.f, bw = 0.f;
        int j = r0 + grp;
        for (; j + 4 < r1; j += 8) {
            const int s0 = adj[j];
            const int s1 = adj[j + 4];
            const float4 v0 = ((const float4*)(xsrc + (size_t)s0 * DIM))[col];
            const float4 v1 = ((const float4*)(xsrc + (size_t)s1 * DIM))[col];
            ax += v0.x; ay += v0.y; az += v0.z; aw += v0.w;
            bx += v1.x; by += v1.y; bz += v1.z; bw += v1.w;
        }
        if (j < r1) {
            const int s0 = adj[j];
            const float4 v0 = ((const float4*)(xsrc + (size_t)s0 * DIM))[col];
            ax += v0.x; ay += v0.y; az += v0.z; aw += v0.w;
        }
        ax += bx; ay += by; az += bz; aw += bw;
        ax += __shfl_xor(ax, 16); ay += __shfl_xor(ay, 16);
        az += __shfl_xor(az, 16); aw += __shfl_xor(aw, 16);
        ax += __shfl_xor(ax, 32); ay += __shfl_xor(ay, 32);
        az += __shfl_xor(az, 32); aw += __shfl_xor(aw, 32);
        if (grp == 0) {
            const float inv = 1.0f / fmaxf((float)(r1 - r0), 1.0f);
            ((float4*)(agg + (size_t)(i - n0) * DIM))[col] =
                make_float4(ax * inv, ay * inv, az * inv, aw * inv);
        }
    }
}

// ---------------------------------------------------------------------------
// Transform tile: C[64 nodes][64] = [agg | xdst][64][128] @ [Wl;Wr][128][64]+b.
// Staging is fully coalesced float4 reads from agg (relative n0) and xdst
// (absolute), written into the XOR-swizzled sAX layout (see round-4 notes).
// Safe for xdst == out: each block stages exactly the rows it later writes.
template <int RELU>
__global__ __launch_bounds__(256) void
transform_tile_kernel(const float* __restrict__ agg,
                      const float* __restrict__ xdst,
                      const float* __restrict__ Wl,
                      const float* __restrict__ Wr,
                      const float* __restrict__ bl,
                      float* __restrict__ out,
                      int n0, int n1) {
    __shared__ float sAX[128 * 64];  // row k, col = swizzled node
    __shared__ float sW[128 * 64];   // rows 0..63 = Wl, 64..127 = Wr

    const int tid = threadIdx.x;
    {
        const float4* wl4 = (const float4*)Wl;
        const float4* wr4 = (const float4*)Wr;
        float4* sw4 = (float4*)sW;
#pragma unroll
        for (int i = 0; i < 4; ++i) {
            sw4[tid + 256 * i] = wl4[tid + 256 * i];
            sw4[1024 + tid + 256 * i] = wr4[tid + 256 * i];
        }
    }
    const int base = n0 + blockIdx.x * 64;
#pragma unroll
    for (int rep = 0; rep < 4; ++rep) {
        const int idx = rep * 256 + tid;   // 0..1023
        const int ln  = idx >> 4;          // local node 0..63
        const int c   = idx & 15;          // float4 column 0..15
        const int node = base + ln;
        const int pc = ((((ln >> 2) ^ c) << 2) | (ln & 3));
        float4 av = make_float4(0.f, 0.f, 0.f, 0.f);
        float4 xv = make_float4(0.f, 0.f, 0.f, 0.f);
        if (node < n1) {
            av = ((const float4*)(agg + (size_t)(node - n0) * DIM))[c];
            xv = ((const float4*)(xdst + (size_t)node * DIM))[c];
        }
        sAX[(4 * c + 0) * 64 + pc] = av.x;
        sAX[(4 * c + 1) * 64 + pc] = av.y;
        sAX[(4 * c + 2) * 64 + pc] = av.z;
        sAX[(4 * c + 3) * 64 + pc] = av.w;
        sAX[(64 + 4 * c + 0) * 64 + pc] = xv.x;
        sAX[(64 + 4 * c + 1) * 64 + pc] = xv.y;
        sAX[(64 + 4 * c + 2) * 64 + pc] = xv.z;
        sAX[(64 + 4 * c + 3) * 64 + pc] = xv.w;
    }
    __syncthreads();

    const int rq = tid >> 4;   // node quad 0..15
    const int cq = tid & 15;   // dim quad 0..15
    const float4 bv = ((const float4*)bl)[cq];
    float4 a0 = bv, a1 = bv, a2 = bv, a3 = bv;
#pragma unroll 4
    for (int k = 0; k < 128; ++k) {
        const int g = (k >> 2) & 15;
        const float4 av = *(const float4*)&sAX[k * 64 + ((rq ^ g) << 2)];
        const float4 wv = *(const float4*)&sW[k * 64 + (cq << 2)];
        a0.x += av.x * wv.x; a0.y += av.x * wv.y; a0.z += av.x * wv.z; a0.w += av.x * wv.w;
        a1.x += av.y * wv.x; a1.y += av.y * wv.y; a1.z += av.y * wv.z; a1.w += av.y * wv.w;
        a2.x += av.z * wv.x; a2.y += av.z * wv.y; a2.z += av.z * wv.z; a2.w += av.z * wv.w;
        a3.x += av.w * wv.x; a3.y += av.w * wv.y; a3.z += av.w * wv.z; a3.w += av.w * wv.w;
    }
    float4 r[4] = {a0, a1, a2, a3};
#pragma unroll
    for (int i = 0; i < 4; ++i) {
        const int node = base + 4 * rq + i;
        if (node < n1) {
            float4 v = r[i];
            if (RELU) {
                v.x = fmaxf(v.x, 0.f); v.y = fmaxf(v.y, 0.f);
                v.z = fmaxf(v.z, 0.f); v.w = fmaxf(v.w, 0.f);
            }
            ((float4*)(out + (size_t)node * DIM))[cq] = v;
        }
    }
}

// ---------------------------------------------------------------------------
extern "C" void kernel_launch(void* const* d_in, const int* in_sizes, int n_in,
                              void* d_out, int out_size, void* d_ws, size_t ws_size,
                              hipStream_t stream) {
    const float* x_user  = (const float*)d_in[0];
    const float* x_movie = (const float*)d_in[1];
    const void*  e_src   = d_in[2];
    const void*  e_dst   = d_in[3];
    const float* W1_um_l = (const float*)d_in[4];
    const float* W1_um_r = (const float*)d_in[5];
    const float* W1_mu_l = (const float*)d_in[6];
    const float* W1_mu_r = (const float*)d_in[7];
    const float* W2_um_l = (const float*)d_in[8];
    const float* W2_um_r = (const float*)d_in[9];
    const float* W2_mu_l = (const float*)d_in[10];
    const float* W2_mu_r = (const float*)d_in[11];
    const float* b1_um = (const float*)d_in[12];
    const float* b1_mu = (const float*)d_in[13];
    const float* b2_um = (const float*)d_in[14];
    const float* b2_mu = (const float*)d_in[15];
    const int nE = in_sizes[2];
    const int cpb = (nE + G_SC - 1) / G_SC;

    // workspace carve-up (256B aligned); peak ~70MB
    char* ws = (char*)d_ws;
    size_t off = 0;
    auto carve = [&](size_t bytes) {
        void* p = ws + off;
        off += (bytes + 255) & ~(size_t)255;
        return p;
    };
    int*      flag   = (int*)carve(4);
    int*      rp_u   = (int*)carve(((size_t)NU + 1) * 4);
    int*      rp_m   = (int*)carve(((size_t)NM + 1) * 4);
    int*      cur_u  = (int*)carve((size_t)NU * 4);
    int*      cur_m  = (int*)carve((size_t)NM * 4);
    int*      bsum_u = (int*)carve(128 * 4);
    int*      bsum_m = (int*)carve(128 * 4);
    int*      hist_m = (int*)carve((size_t)MBK * G_SC * 4);
    int*      hist_u = (int*)carve((size_t)MBK * G_SC * 4);
    int*      bend_m = (int*)carve(MBK * 4);
    int*      bend_u = (int*)carve(MBK * 4);
    int*      adj_u  = (int*)carve((size_t)nE * 4);
    int*      adj_m  = (int*)carve((size_t)nE * 4);
    // overlay: phase A = pr_m|pr_u (2*nE*4); phase B = agg (UCH rows) + m1
    size_t ovl_bytes = (size_t)2 * nE * 4;
    size_t phb_bytes = ((size_t)UCH + NM) * DIM * 4;
    if (phb_bytes > ovl_bytes) ovl_bytes = phb_bytes;
    char*     ovl    = (char*)carve(ovl_bytes);
    unsigned* pr_m   = (unsigned*)ovl;                       // phase A
    unsigned* pr_u   = (unsigned*)(ovl + (size_t)nE * 4);    // phase A
    float*    agg    = (float*)ovl;                          // phase B
    float*    m1     = (float*)(ovl + (size_t)UCH * DIM * 4);// phase B

    float* u2 = (float*)d_out;                    // [NU,64]; also u1 (in-place)
    float* m2 = (float*)d_out + (size_t)NU * DIM; // [NM,64]
    float* u1 = u2;

    // ---- build CSR (both directions) via deterministic two-level binning ----
    hipMemsetAsync(rp_u, 0, ((size_t)NU + 1) * 4, stream);
    hipMemsetAsync(rp_m, 0, ((size_t)NM + 1) * 4, stream);
    detect_idx_kernel<<<1, 256, 0, stream>>>((const unsigned int*)e_src, flag);

    count_kernel<<<G_SC, 256, 0, stream>>>(e_src, e_dst, flag, rp_u, rp_m,
                                           hist_m, hist_u, nE, cpb);

    const int nbU = (NU + SCAN_CHUNK - 1) / SCAN_CHUNK;
    const int nbM = (NM + SCAN_CHUNK - 1) / SCAN_CHUNK;
    scan_block_sums<<<nbU, 256, 0, stream>>>(rp_u, bsum_u, NU);
    scan_block_sums<<<nbM, 256, 0, stream>>>(rp_m, bsum_m, NM);
    scan_bsum<<<1, 64, 0, stream>>>(bsum_u, nbU);
    scan_bsum<<<1, 64, 0, stream>>>(bsum_m, nbM);
    scan_apply<<<nbU, 256, 0, stream>>>(rp_u, bsum_u, NU, nE);
    scan_apply<<<nbM, 256, 0, stream>>>(rp_m, bsum_m, NM, nE);
    hist_scan_kernel<<<2, 256, 0, stream>>>(hist_m, hist_u, bend_m, bend_u, nE);

    hipMemcpyAsync(cur_u, rp_u, (size_t)NU * 4, hipMemcpyDeviceToDevice, stream);
    hipMemcpyAsync(cur_m, rp_m, (size_t)NM * 4, hipMemcpyDeviceToDevice, stream);

    pair_scatter_kernel<<<G_SC, 256, 0, stream>>>(e_src, e_dst, flag,
                                                  hist_m, hist_u, pr_m, pr_u,
                                                  nE, cpb);
    pair_fill_kernel<<<1024, 256, 0, stream>>>(pr_m, bend_m, cur_m, adj_m,
                                               18, MB_M, nE);
    pair_fill_kernel<<<1024, 256, 0, stream>>>(pr_u, bend_u, cur_u, adj_u,
                                               17, MB_U, nE);
    // pr_m/pr_u/hist dead from here; overlay switches to agg/m1.

    const int GB  = 12500;                     // gather blocks (~2 nodes/wave)
    const int TBM = (NM + 63) / 64;            // transform blocks, movie
    const int TBU = (UCH + 63) / 64;           // transform blocks, user chunk

    // ---- layer 1 ----
    gather_mean_kernel<<<GB, 256, 0, stream>>>(x_user, rp_m, adj_m, agg, 0, NM);
    transform_tile_kernel<1><<<TBM, 256, 0, stream>>>(agg, x_movie,
        W1_um_l, W1_um_r, b1_um, m1, 0, NM);
    gather_mean_kernel<<<GB, 256, 0, stream>>>(x_movie, rp_u, adj_u, agg, 0, UCH);
    transform_tile_kernel<1><<<TBU, 256, 0, stream>>>(agg, x_user,
        W1_mu_l, W1_mu_r, b1_mu, u1, 0, UCH);
    gather_mean_kernel<<<GB, 256, 0, stream>>>(x_movie, rp_u, adj_u, agg, UCH, NU);
    transform_tile_kernel<1><<<TBU, 256, 0, stream>>>(agg, x_user,
        W1_mu_l, W1_mu_r, b1_mu, u1, UCH, NU);

    // ---- layer 2 ----
    // movie first: reads ALL of u1 before any u2 overwrite
    gather_mean_kernel<<<GB, 256, 0, stream>>>(u1, rp_m, adj_m, agg, 0, NM);
    transform_tile_kernel<0><<<TBM, 256, 0, stream>>>(agg, m1,
        W2_um_l, W2_um_r, b2_um, m2, 0, NM);
    // user chunks: gathers read m1 only; transform overwrites u1 rows per-tile
    gather_mean_kernel<<<GB, 256, 0, stream>>>(m1, rp_u, adj_u, agg, 0, UCH);
    transform_tile_kernel<0><<<TBU, 256, 0, stream>>>(agg, u1,
        W2_mu_l, W2_mu_r, b2_mu, u2, 0, UCH);
    gather_mean_kernel<<<GB, 256, 0, stream>>>(m1, rp_u, adj_u, agg, UCH, NU);
    transform_tile_kernel<0><<<TBU, 256, 0, stream>>>(agg, u1,
        W2_mu_l, W2_mu_r, b2_mu, u2, UCH, NU);
}

// Round 8
// 778.686 us; speedup vs baseline: 3.1367x; 1.1962x over previous
//
#include <hip/hip_runtime.h>
#include <stdint.h>

#define NU 200000
#define NM 100000
#define DIM 64
#define UCH 100000       // user-direction chunk (agg buffer sized for 100k nodes)
#define SCAN_CHUNK 2048
#define MBK2 32          // buckets per direction
#define SP_M 3125        // movie node span per bucket (NM/32)
#define SP_U 6250        // user  node span per bucket (NU/32)
#define G_SC 1024        // blocks for count/pair_scatter (fixed chunk assignment)

// ---------------------------------------------------------------------------
// Detect whether edge index arrays are int64 or int32.
__global__ void detect_idx_kernel(const unsigned int* __restrict__ words,
                                  int* __restrict__ flag) {
    __shared__ int nz;
    if (threadIdx.x == 0) nz = 0;
    __syncthreads();
    for (int i = threadIdx.x; i < 2048; i += blockDim.x)
        if (words[2 * i + 1] != 0u) nz = 1;
    __syncthreads();
    if (threadIdx.x == 0) *flag = (nz == 0) ? 1 : 0;   // 1 => int64
}

__device__ __forceinline__ int load_idx(const void* __restrict__ p, int e, int is64) {
    if (is64) return (int)((const long long*)p)[e];
    return ((const int*)p)[e];
}

// ---------------------------------------------------------------------------
// Per-block 32-bucket histograms, both directions (bucket-major layout
// hist[b*G_SC + blk]); FIXED per-block edge chunks so pair_scatter can
// reproduce the assignment. NO per-node atomics (degrees come later from the
// pair arrays — avoids the 125MB atomic-RMW line ping-pong across XCDs).
__global__ void count_kernel(const void* __restrict__ es, const void* __restrict__ ed,
                             const int* __restrict__ flag,
                             int* __restrict__ hist_m, int* __restrict__ hist_u,
                             int nE, int cpb) {
    __shared__ int h[2 * MBK2];
    if (threadIdx.x < 2 * MBK2) h[threadIdx.x] = 0;
    __syncthreads();
    const int is64 = *flag;
    const int e0 = blockIdx.x * cpb;
    const int e1 = min(nE, e0 + cpb);
    for (int e = e0 + threadIdx.x; e < e1; e += blockDim.x) {
        int s = load_idx(es, e, is64);
        int d = load_idx(ed, e, is64);
        atomicAdd(&h[(unsigned)d / SP_M], 1);
        atomicAdd(&h[MBK2 + (unsigned)s / SP_U], 1);
    }
    __syncthreads();
    if (threadIdx.x < MBK2)
        hist_m[threadIdx.x * G_SC + blockIdx.x] = h[threadIdx.x];
    else if (threadIdx.x < 2 * MBK2)
        hist_u[(threadIdx.x - MBK2) * G_SC + blockIdx.x] = h[threadIdx.x];
}

// ---------------------------------------------------------------------------
// Exclusive scan over n ints, 3 phases (chunk = 2048 = 256 thr x 8).
__global__ void scan_block_sums(const int* __restrict__ a, int* __restrict__ bsum, int n) {
    int base = blockIdx.x * SCAN_CHUNK + threadIdx.x * 8;
    int tot = 0;
#pragma unroll
    for (int k = 0; k < 8; ++k) { int i = base + k; if (i < n) tot += a[i]; }
    __shared__ int sc[256];
    sc[threadIdx.x] = tot;
    __syncthreads();
    for (int off = 128; off > 0; off >>= 1) {
        if (threadIdx.x < off) sc[threadIdx.x] += sc[threadIdx.x + off];
        __syncthreads();
    }
    if (threadIdx.x == 0) bsum[blockIdx.x] = sc[0];
}

__global__ void scan_bsum(int* __restrict__ bsum, int nb) {
    if (blockIdx.x == 0 && threadIdx.x == 0) {
        int acc = 0;
        for (int i = 0; i < nb; ++i) { int v = bsum[i]; bsum[i] = acc; acc += v; }
    }
}

__global__ void scan_apply(int* __restrict__ a, const int* __restrict__ bsum, int n, int nE) {
    const int t = threadIdx.x;
    int base = blockIdx.x * SCAN_CHUNK + t * 8;
    int v[8];
    int tot = 0;
#pragma unroll
    for (int k = 0; k < 8; ++k) { int i = base + k; v[k] = (i < n) ? a[i] : 0; tot += v[k]; }
    __shared__ int sc[256];
    sc[t] = tot;
    __syncthreads();
    for (int off = 1; off < 256; off <<= 1) {
        int x = (t >= off) ? sc[t - off] : 0;
        __syncthreads();
        sc[t] += x;
        __syncthreads();
    }
    int excl = bsum[blockIdx.x] + sc[t] - tot;
#pragma unroll
    for (int k = 0; k < 8; ++k) { int i = base + k; if (i < n) a[i] = excl; excl += v[k]; }
    if (blockIdx.x == 0 && t == 0) a[n] = nE;
}

// ---------------------------------------------------------------------------
// Exclusive scan of one direction's per-block bucket histogram (32*G_SC ints,
// bucket-major) in place; emits bounds[0..32] (bucket starts + nE). 2 blocks.
__global__ __launch_bounds__(1024) void
hist_scan_kernel(int* __restrict__ hist_m, int* __restrict__ hist_u,
                 int* __restrict__ bounds_m, int* __restrict__ bounds_u, int nE) {
    int* hist   = (blockIdx.x == 0) ? hist_m : hist_u;
    int* bounds = (blockIdx.x == 0) ? bounds_m : bounds_u;
    const int t = threadIdx.x;          // 1024 threads x 32 = 32768 = 32*G_SC
    const int base = t * 32;
    int v[32];
    int tot = 0;
#pragma unroll
    for (int k = 0; k < 32; ++k) { v[k] = hist[base + k]; tot += v[k]; }
    __shared__ int sc[1024];
    sc[t] = tot;
    __syncthreads();
    for (int off = 1; off < 1024; off <<= 1) {
        int x = (t >= off) ? sc[t - off] : 0;
        __syncthreads();
        sc[t] += x;
        __syncthreads();
    }
    int excl = sc[t] - tot;
#pragma unroll
    for (int k = 0; k < 32; ++k) { int tmp = v[k]; hist[base + k] = excl; excl += tmp; }
    __syncthreads();
    if (t < MBK2) bounds[t] = hist[t * G_SC];
    else if (t == MBK2) bounds[MBK2] = nE;
}

// ---------------------------------------------------------------------------
// Level-1 scatter, deterministic: block re-reads its fixed edge chunk, reserves
// slots from 64 LDS cursors (init = scanned per-block offsets), writes packed
// (dlocal,src) pairs into its exclusive per-bucket chunks. NO global atomics.
__global__ void pair_scatter_kernel(const void* __restrict__ es,
                                    const void* __restrict__ ed,
                                    const int* __restrict__ flag,
                                    const int* __restrict__ hist_m,
                                    const int* __restrict__ hist_u,
                                    unsigned* __restrict__ pr_m,
                                    unsigned* __restrict__ pr_u,
                                    int nE, int cpb) {
    __shared__ int cur[2 * MBK2];
    if (threadIdx.x < MBK2)
        cur[threadIdx.x] = hist_m[threadIdx.x * G_SC + blockIdx.x];
    else if (threadIdx.x < 2 * MBK2)
        cur[threadIdx.x] = hist_u[(threadIdx.x - MBK2) * G_SC + blockIdx.x];
    __syncthreads();
    const int is64 = *flag;
    const int e0 = blockIdx.x * cpb;
    const int e1 = min(nE, e0 + cpb);
    for (int e = e0 + threadIdx.x; e < e1; e += blockDim.x) {
        const int s = load_idx(es, e, is64);
        const int d = load_idx(ed, e, is64);
        const int b0 = (unsigned)d / SP_M;
        const int b1 = (unsigned)s / SP_U;
        const int p0 = atomicAdd(&cur[b0], 1);
        pr_m[p0] = ((unsigned)(d - b0 * SP_M) << 18) | (unsigned)s;
        const int p1 = atomicAdd(&cur[MBK2 + b1], 1);
        pr_u[p1] = ((unsigned)(s - b1 * SP_U) << 17) | (unsigned)d;
    }
}

// ---------------------------------------------------------------------------
// Per-bucket degree count from the pair arrays: 64 blocks (32 movie + 32 user),
// LDS histogram over the bucket's node span, one coalesced non-atomic write.
__global__ __launch_bounds__(1024) void
deg_count_kernel(const unsigned* __restrict__ pr_m, const unsigned* __restrict__ pr_u,
                 const int* __restrict__ bounds_m, const int* __restrict__ bounds_u,
                 int* __restrict__ rp_m, int* __restrict__ rp_u) {
    __shared__ int h[SP_U];
    const int b = blockIdx.x;
    const bool mv = (b < MBK2);
    const int bb = mv ? b : b - MBK2;
    const int span  = mv ? SP_M : SP_U;
    const int shift = mv ? 18 : 17;
    const unsigned* pr = mv ? pr_m : pr_u;
    const int* bounds  = mv ? bounds_m : bounds_u;
    int* rp = mv ? rp_m : rp_u;
    const int s0 = bounds[bb], s1 = bounds[bb + 1];
    for (int i = threadIdx.x; i < span; i += blockDim.x) h[i] = 0;
    __syncthreads();
    for (int i = s0 + threadIdx.x; i < s1; i += blockDim.x)
        atomicAdd(&h[pr[i] >> shift], 1);
    __syncthreads();
    const int nb = bb * span;
    for (int i = threadIdx.x; i < span; i += blockDim.x) rp[nb + i] = h[i];
}

// ---------------------------------------------------------------------------
// Level-2: scatter bucket-grouped pairs to exact per-node adj slots. Bucket
// found by 5-step binary search over bounds (LDS). Writes cluster inside a
// rolling ~12-25KB cur window + bucket-local adj region -> L2-coalesced.
__global__ void pair_fill_kernel(const unsigned* __restrict__ pr,
                                 const int* __restrict__ bounds,
                                 int* __restrict__ cur, int* __restrict__ adj,
                                 int shift, int bspan, int nE) {
    __shared__ int sb[MBK2 + 1];
    if (threadIdx.x <= MBK2) sb[threadIdx.x] = bounds[threadIdx.x];
    __syncthreads();
    const unsigned mask = (1u << shift) - 1u;
    const int stride = gridDim.x * blockDim.x;
    for (int i = blockIdx.x * blockDim.x + threadIdx.x; i < nE; i += stride) {
        const unsigned w = pr[i];
        int lo = 0, hi = MBK2;
#pragma unroll
        for (int it = 0; it < 5; ++it) {
            const int mid = (lo + hi) >> 1;
            if (i >= sb[mid]) lo = mid; else hi = mid;
        }
        const int d = lo * bspan + (int)(w >> shift);
        const int s = (int)(w & mask);
        adj[atomicAdd(&cur[d], 1)] = s;
    }
}

// ---------------------------------------------------------------------------
// Mean-aggregate gather (unchanged from round 7): no LDS, high occupancy/MLP.
__global__ __launch_bounds__(256) void
gather_mean_kernel(const float* __restrict__ xsrc,
                   const int* __restrict__ rowptr,
                   const int* __restrict__ adj,
                   float* __restrict__ agg,
                   int n0, int n1) {
    const int lane = threadIdx.x & 63;
    const int grp  = lane >> 4;
    const int col  = lane & 15;
    const int wid  = (blockIdx.x * blockDim.x + threadIdx.x) >> 6;
    const int nw   = (gridDim.x * blockDim.x) >> 6;
    for (int i = n0 + wid; i < n1; i += nw) {
        const int r0 = rowptr[i], r1 = rowptr[i + 1];
        float ax = 0.f, ay = 0.f, az = 0.f, aw = 0.f;
        float bx = 0.f, by = 0.f, bz = 0.f, bw = 0.f;
        int j = r0 + grp;
        for (; j + 4 < r1; j += 8) {
            const int s0 = adj[j];
            const int s1 = adj[j + 4];
            const float4 v0 = ((const float4*)(xsrc + (size_t)s0 * DIM))[col];
            const float4 v1 = ((const float4*)(xsrc + (size_t)s1 * DIM))[col];
            ax += v0.x; ay += v0.y; az += v0.z; aw += v0.w;
            bx += v1.x; by += v1.y; bz += v1.z; bw += v1.w;
        }
        if (j < r1) {
            const int s0 = adj[j];
            const float4 v0 = ((const float4*)(xsrc + (size_t)s0 * DIM))[col];
            ax += v0.x; ay += v0.y; az += v0.z; aw += v0.w;
        }
        ax += bx; ay += by; az += bz; aw += bw;
        ax += __shfl_xor(ax, 16); ay += __shfl_xor(ay, 16);
        az += __shfl_xor(az, 16); aw += __shfl_xor(aw, 16);
        ax += __shfl_xor(ax, 32); ay += __shfl_xor(ay, 32);
        az += __shfl_xor(az, 32); aw += __shfl_xor(aw, 32);
        if (grp == 0) {
            const float inv = 1.0f / fmaxf((float)(r1 - r0), 1.0f);
            ((float4*)(agg + (size_t)(i - n0) * DIM))[col] =
                make_float4(ax * inv, ay * inv, az * inv, aw * inv);
        }
    }
}

// ---------------------------------------------------------------------------
// Transform tile (unchanged from round 7).
template <int RELU>
__global__ __launch_bounds__(256) void
transform_tile_kernel(const float* __restrict__ agg,
                      const float* __restrict__ xdst,
                      const float* __restrict__ Wl,
                      const float* __restrict__ Wr,
                      const float* __restrict__ bl,
                      float* __restrict__ out,
                      int n0, int n1) {
    __shared__ float sAX[128 * 64];
    __shared__ float sW[128 * 64];

    const int tid = threadIdx.x;
    {
        const float4* wl4 = (const float4*)Wl;
        const float4* wr4 = (const float4*)Wr;
        float4* sw4 = (float4*)sW;
#pragma unroll
        for (int i = 0; i < 4; ++i) {
            sw4[tid + 256 * i] = wl4[tid + 256 * i];
            sw4[1024 + tid + 256 * i] = wr4[tid + 256 * i];
        }
    }
    const int base = n0 + blockIdx.x * 64;
#pragma unroll
    for (int rep = 0; rep < 4; ++rep) {
        const int idx = rep * 256 + tid;
        const int ln  = idx >> 4;
        const int c   = idx & 15;
        const int node = base + ln;
        const int pc = ((((ln >> 2) ^ c) << 2) | (ln & 3));
        float4 av = make_float4(0.f, 0.f, 0.f, 0.f);
        float4 xv = make_float4(0.f, 0.f, 0.f, 0.f);
        if (node < n1) {
            av = ((const float4*)(agg + (size_t)(node - n0) * DIM))[c];
            xv = ((const float4*)(xdst + (size_t)node * DIM))[c];
        }
        sAX[(4 * c + 0) * 64 + pc] = av.x;
        sAX[(4 * c + 1) * 64 + pc] = av.y;
        sAX[(4 * c + 2) * 64 + pc] = av.z;
        sAX[(4 * c + 3) * 64 + pc] = av.w;
        sAX[(64 + 4 * c + 0) * 64 + pc] = xv.x;
        sAX[(64 + 4 * c + 1) * 64 + pc] = xv.y;
        sAX[(64 + 4 * c + 2) * 64 + pc] = xv.z;
        sAX[(64 + 4 * c + 3) * 64 + pc] = xv.w;
    }
    __syncthreads();

    const int rq = tid >> 4;
    const int cq = tid & 15;
    const float4 bv = ((const float4*)bl)[cq];
    float4 a0 = bv, a1 = bv, a2 = bv, a3 = bv;
#pragma unroll 4
    for (int k = 0; k < 128; ++k) {
        const int g = (k >> 2) & 15;
        const float4 av = *(const float4*)&sAX[k * 64 + ((rq ^ g) << 2)];
        const float4 wv = *(const float4*)&sW[k * 64 + (cq << 2)];
        a0.x += av.x * wv.x; a0.y += av.x * wv.y; a0.z += av.x * wv.z; a0.w += av.x * wv.w;
        a1.x += av.y * wv.x; a1.y += av.y * wv.y; a1.z += av.y * wv.z; a1.w += av.y * wv.w;
        a2.x += av.z * wv.x; a2.y += av.z * wv.y; a2.z += av.z * wv.z; a2.w += av.z * wv.w;
        a3.x += av.w * wv.x; a3.y += av.w * wv.y; a3.z += av.w * wv.z; a3.w += av.w * wv.w;
    }
    float4 r[4] = {a0, a1, a2, a3};
#pragma unroll
    for (int i = 0; i < 4; ++i) {
        const int node = base + 4 * rq + i;
        if (node < n1) {
            float4 v = r[i];
            if (RELU) {
                v.x = fmaxf(v.x, 0.f); v.y = fmaxf(v.y, 0.f);
                v.z = fmaxf(v.z, 0.f); v.w = fmaxf(v.w, 0.f);
            }
            ((float4*)(out + (size_t)node * DIM))[cq] = v;
        }
    }
}

// ---------------------------------------------------------------------------
extern "C" void kernel_launch(void* const* d_in, const int* in_sizes, int n_in,
                              void* d_out, int out_size, void* d_ws, size_t ws_size,
                              hipStream_t stream) {
    const float* x_user  = (const float*)d_in[0];
    const float* x_movie = (const float*)d_in[1];
    const void*  e_src   = d_in[2];
    const void*  e_dst   = d_in[3];
    const float* W1_um_l = (const float*)d_in[4];
    const float* W1_um_r = (const float*)d_in[5];
    const float* W1_mu_l = (const float*)d_in[6];
    const float* W1_mu_r = (const float*)d_in[7];
    const float* W2_um_l = (const float*)d_in[8];
    const float* W2_um_r = (const float*)d_in[9];
    const float* W2_mu_l = (const float*)d_in[10];
    const float* W2_mu_r = (const float*)d_in[11];
    const float* b1_um = (const float*)d_in[12];
    const float* b1_mu = (const float*)d_in[13];
    const float* b2_um = (const float*)d_in[14];
    const float* b2_mu = (const float*)d_in[15];
    const int nE = in_sizes[2];
    const int cpb = (nE + G_SC - 1) / G_SC;

    // workspace carve-up (256B aligned); peak ~70MB
    char* ws = (char*)d_ws;
    size_t off = 0;
    auto carve = [&](size_t bytes) {
        void* p = ws + off;
        off += (bytes + 255) & ~(size_t)255;
        return p;
    };
    int*      flag     = (int*)carve(4);
    int*      rp_u     = (int*)carve(((size_t)NU + 1) * 4);
    int*      rp_m     = (int*)carve(((size_t)NM + 1) * 4);
    int*      cur_u    = (int*)carve((size_t)NU * 4);
    int*      cur_m    = (int*)carve((size_t)NM * 4);
    int*      bsum_u   = (int*)carve(128 * 4);
    int*      bsum_m   = (int*)carve(128 * 4);
    int*      hist_m   = (int*)carve((size_t)MBK2 * G_SC * 4);
    int*      hist_u   = (int*)carve((size_t)MBK2 * G_SC * 4);
    int*      bounds_m = (int*)carve((MBK2 + 1) * 4);
    int*      bounds_u = (int*)carve((MBK2 + 1) * 4);
    int*      adj_u    = (int*)carve((size_t)nE * 4);
    int*      adj_m    = (int*)carve((size_t)nE * 4);
    // overlay: phase A = pr_m|pr_u (2*nE*4); phase B = agg (UCH rows) + m1
    size_t ovl_bytes = (size_t)2 * nE * 4;
    size_t phb_bytes = ((size_t)UCH + NM) * DIM * 4;
    if (phb_bytes > ovl_bytes) ovl_bytes = phb_bytes;
    char*     ovl    = (char*)carve(ovl_bytes);
    unsigned* pr_m   = (unsigned*)ovl;                        // phase A
    unsigned* pr_u   = (unsigned*)(ovl + (size_t)nE * 4);     // phase A
    float*    agg    = (float*)ovl;                           // phase B
    float*    m1     = (float*)(ovl + (size_t)UCH * DIM * 4); // phase B

    float* u2 = (float*)d_out;                    // [NU,64]; also u1 (in-place)
    float* m2 = (float*)d_out + (size_t)NU * DIM; // [NM,64]
    float* u1 = u2;

    // ---- build CSR (both directions): radix binning, zero global atomics
    //      except the windowed pair_fill ----
    detect_idx_kernel<<<1, 256, 0, stream>>>((const unsigned int*)e_src, flag);
    count_kernel<<<G_SC, 256, 0, stream>>>(e_src, e_dst, flag,
                                           hist_m, hist_u, nE, cpb);
    hist_scan_kernel<<<2, 1024, 0, stream>>>(hist_m, hist_u,
                                             bounds_m, bounds_u, nE);
    pair_scatter_kernel<<<G_SC, 256, 0, stream>>>(e_src, e_dst, flag,
                                                  hist_m, hist_u, pr_m, pr_u,
                                                  nE, cpb);
    // degrees from bucket-grouped pairs (LDS hist, coalesced writes)
    deg_count_kernel<<<2 * MBK2, 1024, 0, stream>>>(pr_m, pr_u,
                                                    bounds_m, bounds_u,
                                                    rp_m, rp_u);

    const int nbU = (NU + SCAN_CHUNK - 1) / SCAN_CHUNK;
    const int nbM = (NM + SCAN_CHUNK - 1) / SCAN_CHUNK;
    scan_block_sums<<<nbU, 256, 0, stream>>>(rp_u, bsum_u, NU);
    scan_block_sums<<<nbM, 256, 0, stream>>>(rp_m, bsum_m, NM);
    scan_bsum<<<1, 64, 0, stream>>>(bsum_u, nbU);
    scan_bsum<<<1, 64, 0, stream>>>(bsum_m, nbM);
    scan_apply<<<nbU, 256, 0, stream>>>(rp_u, bsum_u, NU, nE);
    scan_apply<<<nbM, 256, 0, stream>>>(rp_m, bsum_m, NM, nE);

    hipMemcpyAsync(cur_u, rp_u, (size_t)NU * 4, hipMemcpyDeviceToDevice, stream);
    hipMemcpyAsync(cur_m, rp_m, (size_t)NM * 4, hipMemcpyDeviceToDevice, stream);

    pair_fill_kernel<<<1024, 256, 0, stream>>>(pr_m, bounds_m, cur_m, adj_m,
                                               18, SP_M, nE);
    pair_fill_kernel<<<1024, 256, 0, stream>>>(pr_u, bounds_u, cur_u, adj_u,
                                               17, SP_U, nE);
    // pr_m/pr_u/hist dead from here; overlay switches to agg/m1.

    const int GB  = 12500;                     // gather blocks (~2 nodes/wave)
    const int TBM = (NM + 63) / 64;            // transform blocks, movie
    const int TBU = (UCH + 63) / 64;           // transform blocks, user chunk

    // ---- layer 1 ----
    gather_mean_kernel<<<GB, 256, 0, stream>>>(x_user, rp_m, adj_m, agg, 0, NM);
    transform_tile_kernel<1><<<TBM, 256, 0, stream>>>(agg, x_movie,
        W1_um_l, W1_um_r, b1_um, m1, 0, NM);
    gather_mean_kernel<<<GB, 256, 0, stream>>>(x_movie, rp_u, adj_u, agg, 0, UCH);
    transform_tile_kernel<1><<<TBU, 256, 0, stream>>>(agg, x_user,
        W1_mu_l, W1_mu_r, b1_mu, u1, 0, UCH);
    gather_mean_kernel<<<GB, 256, 0, stream>>>(x_movie, rp_u, adj_u, agg, UCH, NU);
    transform_tile_kernel<1><<<TBU, 256, 0, stream>>>(agg, x_user,
        W1_mu_l, W1_mu_r, b1_mu, u1, UCH, NU);

    // ---- layer 2 ----
    // movie first: reads ALL of u1 before any u2 overwrite
    gather_mean_kernel<<<GB, 256, 0, stream>>>(u1, rp_m, adj_m, agg, 0, NM);
    transform_tile_kernel<0><<<TBM, 256, 0, stream>>>(agg, m1,
        W2_um_l, W2_um_r, b2_um, m2, 0, NM);
    // user chunks: gathers read m1 only; transform overwrites u1 rows per-tile
    gather_mean_kernel<<<GB, 256, 0, stream>>>(m1, rp_u, adj_u, agg, 0, UCH);
    transform_tile_kernel<0><<<TBU, 256, 0, stream>>>(agg, u1,
        W2_mu_l, W2_mu_r, b2_mu, u2, 0, UCH);
    gather_mean_kernel<<<GB, 256, 0, stream>>>(m1, rp_u, adj_u, agg, UCH, NU);
    transform_tile_kernel<0><<<TBU, 256, 0, stream>>>(agg, u1,
        W2_mu_l, W2_mu_r, b2_mu, u2, UCH, NU);
}

// Round 9
// 640.787 us; speedup vs baseline: 3.8117x; 1.2152x over previous
//
#include <hip/hip_runtime.h>
#include <stdint.h>

#define NU 200000
#define NM 100000
#define DIM 64
#define UCH 100000       // user-direction chunk (agg buffer sized for 100k nodes)
#define SCAN_CHUNK 2048
#define MBK2 64          // buckets per direction
#define SP_M 1563        // movie node span per bucket (ceil(NM/64))
#define SP_U 3125        // user  node span per bucket (NU/64)
#define G_SC 1024        // blocks for count/pair_scatter (fixed chunk assignment)

// ---------------------------------------------------------------------------
// Detect whether edge index arrays are int64 or int32.
__global__ void detect_idx_kernel(const unsigned int* __restrict__ words,
                                  int* __restrict__ flag) {
    __shared__ int nz;
    if (threadIdx.x == 0) nz = 0;
    __syncthreads();
    for (int i = threadIdx.x; i < 2048; i += blockDim.x)
        if (words[2 * i + 1] != 0u) nz = 1;
    __syncthreads();
    if (threadIdx.x == 0) *flag = (nz == 0) ? 1 : 0;   // 1 => int64
}

__device__ __forceinline__ int load_idx(const void* __restrict__ p, int e, int is64) {
    if (is64) return (int)((const long long*)p)[e];
    return ((const int*)p)[e];
}

// ---------------------------------------------------------------------------
// Per-block 64-bucket histograms, both directions (bucket-major layout
// hist[b*G_SC + blk]); FIXED per-block edge chunks so pair_scatter can
// reproduce the assignment. NO per-node atomics.
__global__ void count_kernel(const void* __restrict__ es, const void* __restrict__ ed,
                             const int* __restrict__ flag,
                             int* __restrict__ hist_m, int* __restrict__ hist_u,
                             int nE, int cpb) {
    __shared__ int h[2 * MBK2];
    if (threadIdx.x < 2 * MBK2) h[threadIdx.x] = 0;
    __syncthreads();
    const int is64 = *flag;
    const int e0 = blockIdx.x * cpb;
    const int e1 = min(nE, e0 + cpb);
    for (int e = e0 + threadIdx.x; e < e1; e += blockDim.x) {
        int s = load_idx(es, e, is64);
        int d = load_idx(ed, e, is64);
        atomicAdd(&h[(unsigned)d / SP_M], 1);
        atomicAdd(&h[MBK2 + (unsigned)s / SP_U], 1);
    }
    __syncthreads();
    if (threadIdx.x < MBK2)
        hist_m[threadIdx.x * G_SC + blockIdx.x] = h[threadIdx.x];
    else if (threadIdx.x < 2 * MBK2)
        hist_u[(threadIdx.x - MBK2) * G_SC + blockIdx.x] = h[threadIdx.x];
}

// ---------------------------------------------------------------------------
// Exclusive scan over n ints, 3 phases (chunk = 2048 = 256 thr x 8).
__global__ void scan_block_sums(const int* __restrict__ a, int* __restrict__ bsum, int n) {
    int base = blockIdx.x * SCAN_CHUNK + threadIdx.x * 8;
    int tot = 0;
#pragma unroll
    for (int k = 0; k < 8; ++k) { int i = base + k; if (i < n) tot += a[i]; }
    __shared__ int sc[256];
    sc[threadIdx.x] = tot;
    __syncthreads();
    for (int off = 128; off > 0; off >>= 1) {
        if (threadIdx.x < off) sc[threadIdx.x] += sc[threadIdx.x + off];
        __syncthreads();
    }
    if (threadIdx.x == 0) bsum[blockIdx.x] = sc[0];
}

__global__ void scan_bsum(int* __restrict__ bsum, int nb) {
    if (blockIdx.x == 0 && threadIdx.x == 0) {
        int acc = 0;
        for (int i = 0; i < nb; ++i) { int v = bsum[i]; bsum[i] = acc; acc += v; }
    }
}

__global__ void scan_apply(int* __restrict__ a, const int* __restrict__ bsum, int n, int nE) {
    const int t = threadIdx.x;
    int base = blockIdx.x * SCAN_CHUNK + t * 8;
    int v[8];
    int tot = 0;
#pragma unroll
    for (int k = 0; k < 8; ++k) { int i = base + k; v[k] = (i < n) ? a[i] : 0; tot += v[k]; }
    __shared__ int sc[256];
    sc[t] = tot;
    __syncthreads();
    for (int off = 1; off < 256; off <<= 1) {
        int x = (t >= off) ? sc[t - off] : 0;
        __syncthreads();
        sc[t] += x;
        __syncthreads();
    }
    int excl = bsum[blockIdx.x] + sc[t] - tot;
#pragma unroll
    for (int k = 0; k < 8; ++k) { int i = base + k; if (i < n) a[i] = excl; excl += v[k]; }
    if (blockIdx.x == 0 && t == 0) a[n] = nE;
}

// ---------------------------------------------------------------------------
// Exclusive scan of one direction's per-block bucket histogram (64*G_SC ints,
// bucket-major) in place; emits bounds[0..64] (bucket starts + nE). 2 blocks.
__global__ __launch_bounds__(1024) void
hist_scan_kernel(int* __restrict__ hist_m, int* __restrict__ hist_u,
                 int* __restrict__ bounds_m, int* __restrict__ bounds_u, int nE) {
    int* hist   = (blockIdx.x == 0) ? hist_m : hist_u;
    int* bounds = (blockIdx.x == 0) ? bounds_m : bounds_u;
    const int t = threadIdx.x;          // 1024 threads x 64 = 65536 = 64*G_SC
    const int base = t * 64;
    int v[64];
    int tot = 0;
#pragma unroll
    for (int k = 0; k < 64; ++k) { v[k] = hist[base + k]; tot += v[k]; }
    __shared__ int sc[1024];
    sc[t] = tot;
    __syncthreads();
    for (int off = 1; off < 1024; off <<= 1) {
        int x = (t >= off) ? sc[t - off] : 0;
        __syncthreads();
        sc[t] += x;
        __syncthreads();
    }
    int excl = sc[t] - tot;
#pragma unroll
    for (int k = 0; k < 64; ++k) { int tmp = v[k]; hist[base + k] = excl; excl += tmp; }
    __syncthreads();
    if (t < MBK2) bounds[t] = hist[t * G_SC];
    else if (t == MBK2) bounds[MBK2] = nE;
}

// ---------------------------------------------------------------------------
// Level-1 scatter, deterministic: block re-reads its fixed edge chunk, reserves
// slots from 128 LDS cursors (init = scanned per-block offsets), writes packed
// (dlocal,src) pairs into its exclusive per-bucket chunks. NO global atomics.
__global__ void pair_scatter_kernel(const void* __restrict__ es,
                                    const void* __restrict__ ed,
                                    const int* __restrict__ flag,
                                    const int* __restrict__ hist_m,
                                    const int* __restrict__ hist_u,
                                    unsigned* __restrict__ pr_m,
                                    unsigned* __restrict__ pr_u,
                                    int nE, int cpb) {
    __shared__ int cur[2 * MBK2];
    if (threadIdx.x < MBK2)
        cur[threadIdx.x] = hist_m[threadIdx.x * G_SC + blockIdx.x];
    else if (threadIdx.x < 2 * MBK2)
        cur[threadIdx.x] = hist_u[(threadIdx.x - MBK2) * G_SC + blockIdx.x];
    __syncthreads();
    const int is64 = *flag;
    const int e0 = blockIdx.x * cpb;
    const int e1 = min(nE, e0 + cpb);
    for (int e = e0 + threadIdx.x; e < e1; e += blockDim.x) {
        const int s = load_idx(es, e, is64);
        const int d = load_idx(ed, e, is64);
        const int b0 = (unsigned)d / SP_M;
        const int b1 = (unsigned)s / SP_U;
        const int p0 = atomicAdd(&cur[b0], 1);
        pr_m[p0] = ((unsigned)(d - b0 * SP_M) << 18) | (unsigned)s;
        const int p1 = atomicAdd(&cur[MBK2 + b1], 1);
        pr_u[p1] = ((unsigned)(s - b1 * SP_U) << 17) | (unsigned)d;
    }
}

// ---------------------------------------------------------------------------
// Per-bucket degree count from the pair arrays: 128 blocks (64 movie + 64
// user), LDS histogram over the bucket's node span, coalesced non-atomic write.
__global__ __launch_bounds__(1024) void
deg_count_kernel(const unsigned* __restrict__ pr_m, const unsigned* __restrict__ pr_u,
                 const int* __restrict__ bounds_m, const int* __restrict__ bounds_u,
                 int* __restrict__ rp_m, int* __restrict__ rp_u) {
    __shared__ int h[SP_U];
    const int b = blockIdx.x;
    const bool mv = (b < MBK2);
    const int bb = mv ? b : b - MBK2;
    const int span  = mv ? SP_M : SP_U;
    const int shift = mv ? 18 : 17;
    const unsigned* pr = mv ? pr_m : pr_u;
    const int* bounds  = mv ? bounds_m : bounds_u;
    int* rp = mv ? rp_m : rp_u;
    const int n_tot = mv ? NM : NU;
    const int s0 = bounds[bb], s1 = bounds[bb + 1];
    for (int i = threadIdx.x; i < span; i += blockDim.x) h[i] = 0;
    __syncthreads();
    for (int i = s0 + threadIdx.x; i < s1; i += blockDim.x)
        atomicAdd(&h[pr[i] >> shift], 1);
    __syncthreads();
    const int nb = bb * span;
    for (int i = threadIdx.x; i < span && nb + i < n_tot; i += blockDim.x)
        rp[nb + i] = h[i];
}

// ---------------------------------------------------------------------------
// Level-2 fill: ONE block per bucket -> the bucket's contiguous adj region is
// written by a single XCD (no cross-L2 line ping-pong; lines written back
// once). LDS cursors initialized from rowptr; LDS-atomic slot reservation.
__global__ __launch_bounds__(1024) void
bucket_fill_kernel(const unsigned* __restrict__ pr_m, const unsigned* __restrict__ pr_u,
                   const int* __restrict__ bounds_m, const int* __restrict__ bounds_u,
                   const int* __restrict__ rp_m, const int* __restrict__ rp_u,
                   int* __restrict__ adj_m, int* __restrict__ adj_u) {
    __shared__ int cur[SP_U];
    const int b = blockIdx.x;
    const bool mv = (b < MBK2);
    const int bb = mv ? b : b - MBK2;
    const int span  = mv ? SP_M : SP_U;
    const int shift = mv ? 18 : 17;
    const unsigned mask = (1u << shift) - 1u;
    const unsigned* pr = mv ? pr_m : pr_u;
    const int* bounds  = mv ? bounds_m : bounds_u;
    const int* rp = mv ? rp_m : rp_u;
    int* adj = mv ? adj_m : adj_u;
    const int n_tot = mv ? NM : NU;
    const int nb = bb * span;
    for (int i = threadIdx.x; i < span; i += blockDim.x)
        cur[i] = (nb + i < n_tot) ? rp[nb + i] : 0;
    __syncthreads();
    const int s0 = bounds[bb], s1 = bounds[bb + 1];
    for (int i = s0 + threadIdx.x; i < s1; i += blockDim.x) {
        const unsigned w = pr[i];
        const int slot = atomicAdd(&cur[w >> shift], 1);
        adj[slot] = (int)(w & mask);
    }
}

// ---------------------------------------------------------------------------
// Mean-aggregate gather (unchanged): no LDS, high occupancy/MLP.
__global__ __launch_bounds__(256) void
gather_mean_kernel(const float* __restrict__ xsrc,
                   const int* __restrict__ rowptr,
                   const int* __restrict__ adj,
                   float* __restrict__ agg,
                   int n0, int n1) {
    const int lane = threadIdx.x & 63;
    const int grp  = lane >> 4;
    const int col  = lane & 15;
    const int wid  = (blockIdx.x * blockDim.x + threadIdx.x) >> 6;
    const int nw   = (gridDim.x * blockDim.x) >> 6;
    for (int i = n0 + wid; i < n1; i += nw) {
        const int r0 = rowptr[i], r1 = rowptr[i + 1];
        float ax = 0.f, ay = 0.f, az = 0.f, aw = 0.f;
        float bx = 0.f, by = 0.f, bz = 0.f, bw = 0.f;
        int j = r0 + grp;
        for (; j + 4 < r1; j += 8) {
            const int s0 = adj[j];
            const int s1 = adj[j + 4];
            const float4 v0 = ((const float4*)(xsrc + (size_t)s0 * DIM))[col];
            const float4 v1 = ((const float4*)(xsrc + (size_t)s1 * DIM))[col];
            ax += v0.x; ay += v0.y; az += v0.z; aw += v0.w;
            bx += v1.x; by += v1.y; bz += v1.z; bw += v1.w;
        }
        if (j < r1) {
            const int s0 = adj[j];
            const float4 v0 = ((const float4*)(xsrc + (size_t)s0 * DIM))[col];
            ax += v0.x; ay += v0.y; az += v0.z; aw += v0.w;
        }
        ax += bx; ay += by; az += bz; aw += bw;
        ax += __shfl_xor(ax, 16); ay += __shfl_xor(ay, 16);
        az += __shfl_xor(az, 16); aw += __shfl_xor(aw, 16);
        ax += __shfl_xor(ax, 32); ay += __shfl_xor(ay, 32);
        az += __shfl_xor(az, 32); aw += __shfl_xor(aw, 32);
        if (grp == 0) {
            const float inv = 1.0f / fmaxf((float)(r1 - r0), 1.0f);
            ((float4*)(agg + (size_t)(i - n0) * DIM))[col] =
                make_float4(ax * inv, ay * inv, az * inv, aw * inv);
        }
    }
}

// ---------------------------------------------------------------------------
// Transform tile (unchanged).
template <int RELU>
__global__ __launch_bounds__(256) void
transform_tile_kernel(const float* __restrict__ agg,
                      const float* __restrict__ xdst,
                      const float* __restrict__ Wl,
                      const float* __restrict__ Wr,
                      const float* __restrict__ bl,
                      float* __restrict__ out,
                      int n0, int n1) {
    __shared__ float sAX[128 * 64];
    __shared__ float sW[128 * 64];

    const int tid = threadIdx.x;
    {
        const float4* wl4 = (const float4*)Wl;
        const float4* wr4 = (const float4*)Wr;
        float4* sw4 = (float4*)sW;
#pragma unroll
        for (int i = 0; i < 4; ++i) {
            sw4[tid + 256 * i] = wl4[tid + 256 * i];
            sw4[1024 + tid + 256 * i] = wr4[tid + 256 * i];
        }
    }
    const int base = n0 + blockIdx.x * 64;
#pragma unroll
    for (int rep = 0; rep < 4; ++rep) {
        const int idx = rep * 256 + tid;
        const int ln  = idx >> 4;
        const int c   = idx & 15;
        const int node = base + ln;
        const int pc = ((((ln >> 2) ^ c) << 2) | (ln & 3));
        float4 av = make_float4(0.f, 0.f, 0.f, 0.f);
        float4 xv = make_float4(0.f, 0.f, 0.f, 0.f);
        if (node < n1) {
            av = ((const float4*)(agg + (size_t)(node - n0) * DIM))[c];
            xv = ((const float4*)(xdst + (size_t)node * DIM))[c];
        }
        sAX[(4 * c + 0) * 64 + pc] = av.x;
        sAX[(4 * c + 1) * 64 + pc] = av.y;
        sAX[(4 * c + 2) * 64 + pc] = av.z;
        sAX[(4 * c + 3) * 64 + pc] = av.w;
        sAX[(64 + 4 * c + 0) * 64 + pc] = xv.x;
        sAX[(64 + 4 * c + 1) * 64 + pc] = xv.y;
        sAX[(64 + 4 * c + 2) * 64 + pc] = xv.z;
        sAX[(64 + 4 * c + 3) * 64 + pc] = xv.w;
    }
    __syncthreads();

    const int rq = tid >> 4;
    const int cq = tid & 15;
    const float4 bv = ((const float4*)bl)[cq];
    float4 a0 = bv, a1 = bv, a2 = bv, a3 = bv;
#pragma unroll 4
    for (int k = 0; k < 128; ++k) {
        const int g = (k >> 2) & 15;
        const float4 av = *(const float4*)&sAX[k * 64 + ((rq ^ g) << 2)];
        const float4 wv = *(const float4*)&sW[k * 64 + (cq << 2)];
        a0.x += av.x * wv.x; a0.y += av.x * wv.y; a0.z += av.x * wv.z; a0.w += av.x * wv.w;
        a1.x += av.y * wv.x; a1.y += av.y * wv.y; a1.z += av.y * wv.z; a1.w += av.y * wv.w;
        a2.x += av.z * wv.x; a2.y += av.z * wv.y; a2.z += av.z * wv.z; a2.w += av.z * wv.w;
        a3.x += av.w * wv.x; a3.y += av.w * wv.y; a3.z += av.w * wv.z; a3.w += av.w * wv.w;
    }
    float4 r[4] = {a0, a1, a2, a3};
#pragma unroll
    for (int i = 0; i < 4; ++i) {
        const int node = base + 4 * rq + i;
        if (node < n1) {
            float4 v = r[i];
            if (RELU) {
                v.x = fmaxf(v.x, 0.f); v.y = fmaxf(v.y, 0.f);
                v.z = fmaxf(v.z, 0.f); v.w = fmaxf(v.w, 0.f);
            }
            ((float4*)(out + (size_t)node * DIM))[cq] = v;
        }
    }
}

// ---------------------------------------------------------------------------
extern "C" void kernel_launch(void* const* d_in, const int* in_sizes, int n_in,
                              void* d_out, int out_size, void* d_ws, size_t ws_size,
                              hipStream_t stream) {
    const float* x_user  = (const float*)d_in[0];
    const float* x_movie = (const float*)d_in[1];
    const void*  e_src   = d_in[2];
    const void*  e_dst   = d_in[3];
    const float* W1_um_l = (const float*)d_in[4];
    const float* W1_um_r = (const float*)d_in[5];
    const float* W1_mu_l = (const float*)d_in[6];
    const float* W1_mu_r = (const float*)d_in[7];
    const float* W2_um_l = (const float*)d_in[8];
    const float* W2_um_r = (const float*)d_in[9];
    const float* W2_mu_l = (const float*)d_in[10];
    const float* W2_mu_r = (const float*)d_in[11];
    const float* b1_um = (const float*)d_in[12];
    const float* b1_mu = (const float*)d_in[13];
    const float* b2_um = (const float*)d_in[14];
    const float* b2_mu = (const float*)d_in[15];
    const int nE = in_sizes[2];
    const int cpb = (nE + G_SC - 1) / G_SC;

    // workspace carve-up (256B aligned); peak ~70MB
    char* ws = (char*)d_ws;
    size_t off = 0;
    auto carve = [&](size_t bytes) {
        void* p = ws + off;
        off += (bytes + 255) & ~(size_t)255;
        return p;
    };
    int*      flag     = (int*)carve(4);
    int*      rp_u     = (int*)carve(((size_t)NU + 1) * 4);
    int*      rp_m     = (int*)carve(((size_t)NM + 1) * 4);
    int*      bsum_u   = (int*)carve(128 * 4);
    int*      bsum_m   = (int*)carve(128 * 4);
    int*      hist_m   = (int*)carve((size_t)MBK2 * G_SC * 4);
    int*      hist_u   = (int*)carve((size_t)MBK2 * G_SC * 4);
    int*      bounds_m = (int*)carve((MBK2 + 1) * 4);
    int*      bounds_u = (int*)carve((MBK2 + 1) * 4);
    int*      adj_u    = (int*)carve((size_t)nE * 4);
    int*      adj_m    = (int*)carve((size_t)nE * 4);
    // overlay: phase A = pr_m|pr_u (2*nE*4); phase B = agg (UCH rows) + m1
    size_t ovl_bytes = (size_t)2 * nE * 4;
    size_t phb_bytes = ((size_t)UCH + NM) * DIM * 4;
    if (phb_bytes > ovl_bytes) ovl_bytes = phb_bytes;
    char*     ovl    = (char*)carve(ovl_bytes);
    unsigned* pr_m   = (unsigned*)ovl;                        // phase A
    unsigned* pr_u   = (unsigned*)(ovl + (size_t)nE * 4);     // phase A
    float*    agg    = (float*)ovl;                           // phase B
    float*    m1     = (float*)(ovl + (size_t)UCH * DIM * 4); // phase B

    float* u2 = (float*)d_out;                    // [NU,64]; also u1 (in-place)
    float* m2 = (float*)d_out + (size_t)NU * DIM; // [NM,64]
    float* u1 = u2;

    // ---- build CSR (both directions): radix binning, zero global atomics ----
    detect_idx_kernel<<<1, 256, 0, stream>>>((const unsigned int*)e_src, flag);
    count_kernel<<<G_SC, 256, 0, stream>>>(e_src, e_dst, flag,
                                           hist_m, hist_u, nE, cpb);
    hist_scan_kernel<<<2, 1024, 0, stream>>>(hist_m, hist_u,
                                             bounds_m, bounds_u, nE);
    pair_scatter_kernel<<<G_SC, 256, 0, stream>>>(e_src, e_dst, flag,
                                                  hist_m, hist_u, pr_m, pr_u,
                                                  nE, cpb);
    // degrees from bucket-grouped pairs (LDS hist, coalesced writes)
    deg_count_kernel<<<2 * MBK2, 1024, 0, stream>>>(pr_m, pr_u,
                                                    bounds_m, bounds_u,
                                                    rp_m, rp_u);

    const int nbU = (NU + SCAN_CHUNK - 1) / SCAN_CHUNK;
    const int nbM = (NM + SCAN_CHUNK - 1) / SCAN_CHUNK;
    scan_block_sums<<<nbU, 256, 0, stream>>>(rp_u, bsum_u, NU);
    scan_block_sums<<<nbM, 256, 0, stream>>>(rp_m, bsum_m, NM);
    scan_bsum<<<1, 64, 0, stream>>>(bsum_u, nbU);
    scan_bsum<<<1, 64, 0, stream>>>(bsum_m, nbM);
    scan_apply<<<nbU, 256, 0, stream>>>(rp_u, bsum_u, NU, nE);
    scan_apply<<<nbM, 256, 0, stream>>>(rp_m, bsum_m, NM, nE);

    // fill adj: one block per bucket -> XCD-exclusive write regions
    bucket_fill_kernel<<<2 * MBK2, 1024, 0, stream>>>(pr_m, pr_u,
                                                      bounds_m, bounds_u,
                                                      rp_m, rp_u, adj_m, adj_u);
    // pr_m/pr_u/hist dead from here; overlay switches to agg/m1.

    const int GB  = 12500;                     // gather blocks (~2 nodes/wave)
    const int TBM = (NM + 63) / 64;            // transform blocks, movie
    const int TBU = (UCH + 63) / 64;           // transform blocks, user chunk

    // ---- layer 1 ----
    gather_mean_kernel<<<GB, 256, 0, stream>>>(x_user, rp_m, adj_m, agg, 0, NM);
    transform_tile_kernel<1><<<TBM, 256, 0, stream>>>(agg, x_movie,
        W1_um_l, W1_um_r, b1_um, m1, 0, NM);
    gather_mean_kernel<<<GB, 256, 0, stream>>>(x_movie, rp_u, adj_u, agg, 0, UCH);
    transform_tile_kernel<1><<<TBU, 256, 0, stream>>>(agg, x_user,
        W1_mu_l, W1_mu_r, b1_mu, u1, 0, UCH);
    gather_mean_kernel<<<GB, 256, 0, stream>>>(x_movie, rp_u, adj_u, agg, UCH, NU);
    transform_tile_kernel<1><<<TBU, 256, 0, stream>>>(agg, x_user,
        W1_mu_l, W1_mu_r, b1_mu, u1, UCH, NU);

    // ---- layer 2 ----
    // movie first: reads ALL of u1 before any u2 overwrite
    gather_mean_kernel<<<GB, 256, 0, stream>>>(u1, rp_m, adj_m, agg, 0, NM);
    transform_tile_kernel<0><<<TBM, 256, 0, stream>>>(agg, m1,
        W2_um_l, W2_um_r, b2_um, m2, 0, NM);
    // user chunks: gathers read m1 only; transform overwrites u1 rows per-tile
    gather_mean_kernel<<<GB, 256, 0, stream>>>(m1, rp_u, adj_u, agg, 0, UCH);
    transform_tile_kernel<0><<<TBU, 256, 0, stream>>>(agg, u1,
        W2_mu_l, W2_mu_r, b2_mu, u2, 0, UCH);
    gather_mean_kernel<<<GB, 256, 0, stream>>>(m1, rp_u, adj_u, agg, UCH, NU);
    transform_tile_kernel<0><<<TBU, 256, 0, stream>>>(agg, u1,
        W2_mu_l, W2_mu_r, b2_mu, u2, UCH, NU);
}